// Round 11
// baseline (1360.558 us; speedup 1.0000x reference)
//
#include <hip/hip_runtime.h>
#include <stdint.h>

#define B_    64
#define C_    3
#define H_    224
#define W_    224
#define P_    16
#define GH_   14
#define NP_   196
#define NPP_  224          // NP padded to multiple of 32
#define PD_   768
#define HEADS_ 8
#define VDIM_ 128
#define DIM_  1024
#define DEPTH_ 6
#define NC_   1000
#define EPS_  1e-5f
#define SCALE_ 0.08838834764831845f   // 128^-0.5
#define ROWS_ (B_*NP_)                 // 12544
#define PPITCH_ 232                    // P LDS row pitch (bf16): 116 dwords ≡ 20 mod 32

typedef __bf16 bf16;
typedef __bf16 bfv8 __attribute__((ext_vector_type(8)));
typedef __bf16 bfv4 __attribute__((ext_vector_type(4)));
typedef float  f32x4 __attribute__((ext_vector_type(4)));

#define AS1 __attribute__((address_space(1)))
#define AS3 __attribute__((address_space(3)))

__device__ __forceinline__ void gld_lds16(const bf16* g, bf16* l) {
    __builtin_amdgcn_global_load_lds((const AS1 uint32_t*)g, (AS3 uint32_t*)l, 16, 0, 0);
}

__device__ __forceinline__ f32x4 mfma16(bfv8 a, bfv8 b, f32x4 c) {
    return __builtin_amdgcn_mfma_f32_16x16x32_bf16(a, b, c, 0, 0, 0);
}

// ---------------- zero-fill (float4 grid-stride) -----------------------------
__global__ void zero_f4(float4* __restrict__ p, size_t n4) {
    size_t i = (size_t)blockIdx.x * blockDim.x + threadIdx.x;
    size_t stride = (size_t)gridDim.x * blockDim.x;
    float4 z = {0.f, 0.f, 0.f, 0.f};
    for (; i < n4; i += stride) p[i] = z;
}

// ---------------- fp32 -> bf16 elementwise convert (x4 per thread) -----------
__global__ void conv_bf16(const float* __restrict__ in, bf16* __restrict__ out,
                          size_t n4) {
    size_t i = (size_t)blockIdx.x * blockDim.x + threadIdx.x;
    size_t stride = (size_t)gridDim.x * blockDim.x;
    for (; i < n4; i += stride) {
        float4 v = ((const float4*)in)[i];
        bfv4 o = { (bf16)v.x, (bf16)v.y, (bf16)v.z, (bf16)v.w };
        *(bfv4*)(out + i * 4) = o;
    }
}

// ---------------- block-wide twin reduction ---------------------------------
__device__ inline void block_reduce_2(float& a, float& b) {
    __shared__ float sa[4], sb[4];
    #pragma unroll
    for (int o = 32; o > 0; o >>= 1) {
        a += __shfl_down(a, o);
        b += __shfl_down(b, o);
    }
    int lane = threadIdx.x & 63, wid = threadIdx.x >> 6;
    if (lane == 0) { sa[wid] = a; sb[wid] = b; }
    __syncthreads();
    a = sa[0] + sa[1] + sa[2] + sa[3];
    b = sb[0] + sb[1] + sb[2] + sb[3];
    __syncthreads();
}

// ---------------- patchify + LayerNorm over PD=768 -> bf16 -------------------
__global__ void patchify_ln(const float* __restrict__ img,
                            const float* __restrict__ g,
                            const float* __restrict__ beta,
                            bf16* __restrict__ out) {
    int bn = blockIdx.x;
    int b = bn / NP_, n = bn % NP_;
    int gh = n / GH_, gw = n % GH_;
    int t = threadIdx.x;              // pixel 0..255
    int p1 = t >> 4, p2 = t & 15;
    int row = gh * P_ + p1, col = gw * P_ + p2;
    const float* ip = img + (size_t)b * C_ * H_ * W_ + (size_t)row * W_ + col;
    float v0 = ip[0];
    float v1 = ip[H_ * W_];
    float v2 = ip[2 * H_ * W_];
    float s  = v0 + v1 + v2;
    float s2 = v0 * v0 + v1 * v1 + v2 * v2;
    block_reduce_2(s, s2);
    float mean = s * (1.0f / PD_);
    float var  = s2 * (1.0f / PD_) - mean * mean;
    float r = rsqrtf(var + EPS_);
    int d = t * 3;
    bf16* op = out + (size_t)bn * PD_ + d;
    op[0] = (bf16)((v0 - mean) * r * g[d]     + beta[d]);
    op[1] = (bf16)((v1 - mean) * r * g[d + 1] + beta[d + 1]);
    op[2] = (bf16)((v2 - mean) * r * g[d + 2] + beta[d + 2]);
}

// ---------------- row LayerNorm over DIM=1024: bf16 in -> bf16 out -----------
__global__ void ln_rows(const bf16* __restrict__ in,
                        bf16* __restrict__ outb,
                        const float* __restrict__ g, const float* __restrict__ beta,
                        const float* __restrict__ pos) {
    int r = blockIdx.x;
    int t = threadIdx.x;
    bfv4 iv = *(const bfv4*)(in + (size_t)r * DIM_ + (size_t)t * 4);
    float4 v = { (float)iv[0], (float)iv[1], (float)iv[2], (float)iv[3] };
    float s  = v.x + v.y + v.z + v.w;
    float s2 = v.x * v.x + v.y * v.y + v.z * v.z + v.w * v.w;
    block_reduce_2(s, s2);
    float mean = s * (1.0f / DIM_);
    float var  = s2 * (1.0f / DIM_) - mean * mean;
    float rs = rsqrtf(var + EPS_);
    int n = r % NP_;
    float4 gv = ((const float4*)g)[t];
    float4 bv = ((const float4*)beta)[t];
    float4 o;
    o.x = (v.x - mean) * rs * gv.x + bv.x;
    o.y = (v.y - mean) * rs * gv.y + bv.y;
    o.z = (v.z - mean) * rs * gv.z + bv.z;
    o.w = (v.w - mean) * rs * gv.w + bv.w;
    if (pos) {
        float4 pv = ((const float4*)(pos + (size_t)n * DIM_))[t];
        o.x += pv.x; o.y += pv.y; o.z += pv.z; o.w += pv.w;
    }
    bfv4 ob = { (bf16)o.x, (bf16)o.y, (bf16)o.z, (bf16)o.w };
    *(bfv4*)(outb + (size_t)r * DIM_ + (size_t)t * 4) = ob;
}

// ---------------- big MFMA GEMM: C = A[M,K] @ BT[N,K]^T (+bias) --------------
// requires M%128==0, N%128==0, K%32==0. 256 thr = 4 waves, each 64x64.
// XCD swizzle: groups of 8 m-tiles round-robin so each XCD L2 pins one stripe.
template<bool OUT_BF16>
__global__ __launch_bounds__(256)
void gemm_bt_big(const bf16* __restrict__ A, const bf16* __restrict__ BT,
                 void* __restrict__ Cout, const float* __restrict__ bias,
                 int M, int N, int K) {
    __shared__ bf16 Asm[128 * 32];
    __shared__ bf16 Bsm[128 * 32];
    const int tid = threadIdx.x;
    const int wave = tid >> 6, lane = tid & 63;
    const int MT = gridDim.y, NT = gridDim.x;
    const int flat = blockIdx.y * NT + blockIdx.x;
    const int per = 8 * NT;
    const int group = flat / per;
    const int within = flat % per;
    int gm = MT - group * 8; if (gm > 8) gm = 8;
    const int m0 = (group * 8 + within % gm) * 128;
    const int n0 = (within / gm) * 128;
    const int r16 = lane >> 2;
    const int kc  = (lane & 3) * 8;
    const bf16* Ag0 = A  + (size_t)(m0 + wave * 16 + r16) * K + kc;
    const bf16* Ag1 = Ag0 + (size_t)64 * K;
    const bf16* Bg0 = BT + (size_t)(n0 + wave * 16 + r16) * K + kc;
    const bf16* Bg1 = Bg0 + (size_t)64 * K;
    bf16* Al0 = Asm + wave * 512;
    bf16* Al1 = Asm + 2048 + wave * 512;
    bf16* Bl0 = Bsm + wave * 512;
    bf16* Bl1 = Bsm + 2048 + wave * 512;
    const int qd = lane >> 4, l15 = lane & 15;
    const int wm = (wave >> 1) * 64, wn = (wave & 1) * 64;
    f32x4 acc[4][4] = {};
    for (int k0 = 0; k0 < K; k0 += 32) {
        gld_lds16(Ag0 + k0, Al0);
        gld_lds16(Ag1 + k0, Al1);
        gld_lds16(Bg0 + k0, Bl0);
        gld_lds16(Bg1 + k0, Bl1);
        __syncthreads();
        bfv8 af[4], bfr[4];
        #pragma unroll
        for (int i = 0; i < 4; i++)
            af[i] = *(const bfv8*)(Asm + (wm + i * 16 + l15) * 32 + qd * 8);
        #pragma unroll
        for (int j = 0; j < 4; j++)
            bfr[j] = *(const bfv8*)(Bsm + (wn + j * 16 + l15) * 32 + qd * 8);
        #pragma unroll
        for (int i = 0; i < 4; i++)
            #pragma unroll
            for (int j = 0; j < 4; j++)
                acc[i][j] = mfma16(af[i], bfr[j], acc[i][j]);
        __syncthreads();
    }
    float* Cf = (float*)Cout;
    bf16*  Cb = (bf16*)Cout;
    #pragma unroll
    for (int i = 0; i < 4; i++) {
        int rowb = m0 + wm + i * 16 + qd * 4;
        #pragma unroll
        for (int j = 0; j < 4; j++) {
            int col = n0 + wn + j * 16 + l15;
            float bv = bias ? bias[col] : 0.0f;
            #pragma unroll
            for (int r = 0; r < 4; r++) {
                float v = acc[i][j][r] + bv;
                if (OUT_BF16) Cb[(size_t)(rowb + r) * N + col] = (bf16)v;
                else          Cf[(size_t)(rowb + r) * N + col] = v;
            }
        }
    }
}

// ---------------- small MFMA GEMM: 64x64 tile, 2-level batch -----------------
// gld_lds16 staging: rows beyond M/N read unguarded into adjacent workspace
// (caller-audited). Stores are tail-masked. K%32==0.
template<bool OUT_BF16>
__global__ __launch_bounds__(256)
void gemm_bt_small(const bf16* __restrict__ A, long sA1, long sA2, long lda,
                   const bf16* __restrict__ BT, long sB1, long sB2, long ldb,
                   void* __restrict__ Cout, long sC1, long sC2, long ldc,
                   const float* __restrict__ bias,
                   const bf16* __restrict__ resid, long sR1,
                   int M, int N, int K, float alpha, int zdiv) {
    __shared__ bf16 Asm[64 * 32];
    __shared__ bf16 Bsm[64 * 32];
    const int bz = blockIdx.z;
    const int z1 = bz / zdiv, z2 = bz % zdiv;
    A  += (size_t)z1 * sA1 + (size_t)z2 * sA2;
    BT += (size_t)z1 * sB1 + (size_t)z2 * sB2;
    const int tid = threadIdx.x;
    const int wave = tid >> 6, lane = tid & 63;
    const int m0 = blockIdx.y * 64, n0 = blockIdx.x * 64;
    const int r16 = lane >> 2;
    const int kc  = (lane & 3) * 8;
    const int qd = lane >> 4, l15 = lane & 15;
    const bf16* Ag = A  + (size_t)(m0 + wave * 16 + r16) * lda + kc;
    const bf16* Bg = BT + (size_t)(n0 + wave * 16 + r16) * ldb + kc;
    bf16* Al = Asm + wave * 512;
    bf16* Bl = Bsm + wave * 512;
    f32x4 acc[4] = {};
    for (int k0 = 0; k0 < K; k0 += 32) {
        gld_lds16(Ag + k0, Al);
        gld_lds16(Bg + k0, Bl);
        __syncthreads();
        bfv8 af = *(const bfv8*)(Asm + (wave * 16 + l15) * 32 + qd * 8);
        #pragma unroll
        for (int j = 0; j < 4; j++) {
            bfv8 bv = *(const bfv8*)(Bsm + (j * 16 + l15) * 32 + qd * 8);
            acc[j] = mfma16(af, bv, acc[j]);
        }
        __syncthreads();
    }
    float* Cf = (float*)Cout + (size_t)z1 * sC1 + (size_t)z2 * sC2;
    bf16*  Cb = (bf16*)Cout + (size_t)z1 * sC1 + (size_t)z2 * sC2;
    const bf16* rs = resid ? resid + (size_t)z1 * sR1 : nullptr;
    #pragma unroll
    for (int j = 0; j < 4; j++) {
        int col = n0 + j * 16 + l15;
        if (col >= N) continue;
        float bv = bias ? bias[col] : 0.f;
        #pragma unroll
        for (int r = 0; r < 4; r++) {
            int row = m0 + wave * 16 + qd * 4 + r;
            if (row >= M) continue;
            float v = alpha * acc[j][r] + bv;
            if (rs) v += (float)rs[(size_t)row * ldc + col];
            if (OUT_BF16) Cb[(size_t)row * ldc + col] = (bf16)v;
            else          Cf[(size_t)row * ldc + col] = v;
        }
    }
}

// ---------------- fused softmax + P@V: one block per (64-row stripe, batch) --
// Phase 1: softmax rows of S [fp32, 196 cols] -> P bf16 in LDS [64][232].
// Phase 2: x = P @ fwT^T + resid, K=224. A-frags from LDS, B-frags direct from
// global (no K-loop barriers). fwT pad cols 196..223 are zero (never written).
__global__ __launch_bounds__(256)
void attn_pv(const float* __restrict__ S,      // [B][196][196]
             const bf16* __restrict__ fwT,     // [B][1024][224]
             const bf16* __restrict__ resid,   // h_bf [B][196][1024]
             bf16* __restrict__ xout) {        // x    [B][196][1024]
    __shared__ bf16  P[64 * PPITCH_];
    __shared__ float mred[64][4];
    __shared__ float sred[64][4];
    const int bz = blockIdx.y;
    const int m0 = blockIdx.x * 64;
    const int tid = threadIdx.x;
    const int r = tid >> 2, q = tid & 3;      // row 0..63, quarter 0..3
    const int gr = m0 + r;
    const bool valid = (gr < NP_);
    const float* Sp = S + (size_t)bz * NP_ * NP_ + (size_t)gr * NP_;
    // pass A: row max
    float mq = -1e30f;
    if (valid)
        for (int c = q * 56; c < q * 56 + 56; ++c)
            if (c < NP_) mq = fmaxf(mq, Sp[c]);
    mred[r][q] = mq;
    __syncthreads();
    float m = fmaxf(fmaxf(mred[r][0], mred[r][1]), fmaxf(mred[r][2], mred[r][3]));
    // pass B: e = exp(S - m) -> P (bf16), partial sums
    float sq = 0.f;
    for (int c = q * 56; c < q * 56 + 56; ++c) {
        float e = 0.f;
        if (valid && c < NP_) { e = __expf(Sp[c] - m); sq += e; }
        P[r * PPITCH_ + c] = (bf16)e;
    }
    if (q == 3)
        for (int c = 224; c < PPITCH_; ++c) P[r * PPITCH_ + c] = (bf16)0.f;
    sred[r][q] = sq;
    __syncthreads();
    float l = sred[r][0] + sred[r][1] + sred[r][2] + sred[r][3];
    float rl = (l > 0.f) ? 1.0f / l : 0.f;
    // pass C: P *= 1/l
    for (int c = q * 56; c < q * 56 + 56; ++c)
        P[r * PPITCH_ + c] = (bf16)((float)P[r * PPITCH_ + c] * rl);
    __syncthreads();
    // phase 2: per wave, 64 rows x 64-col stripes over 4 chunks; no barriers.
    const int wave = tid >> 6, lane = tid & 63;
    const int qd = lane >> 4, l15 = lane & 15;
    const bf16* fb = fwT + (size_t)bz * DIM_ * NPP_;
    const bf16* rb = resid + (size_t)bz * NP_ * DIM_;
    bf16* xb = xout + (size_t)bz * NP_ * DIM_;
    for (int cc = 0; cc < 4; ++cc) {
        const int n0 = cc * 256 + wave * 64;
        f32x4 acc[4][4] = {};
        #pragma unroll
        for (int k0 = 0; k0 < NPP_; k0 += 32) {
            bfv8 af[4], bfr[4];
            #pragma unroll
            for (int i = 0; i < 4; i++)
                af[i] = *(const bfv8*)(P + (i * 16 + l15) * PPITCH_ + k0 + qd * 8);
            #pragma unroll
            for (int j = 0; j < 4; j++)
                bfr[j] = *(const bfv8*)(fb + (size_t)(n0 + j * 16 + l15) * NPP_ + k0 + qd * 8);
            #pragma unroll
            for (int i = 0; i < 4; i++)
                #pragma unroll
                for (int j = 0; j < 4; j++)
                    acc[i][j] = mfma16(af[i], bfr[j], acc[i][j]);
        }
        #pragma unroll
        for (int i = 0; i < 4; i++) {
            #pragma unroll
            for (int rr = 0; rr < 4; rr++) {
                int row = m0 + i * 16 + qd * 4 + rr;
                if (row >= NP_) continue;
                #pragma unroll
                for (int j = 0; j < 4; j++) {
                    int col = n0 + j * 16 + l15;
                    float v = acc[i][j][rr] + (float)rb[(size_t)row * DIM_ + col];
                    xb[(size_t)row * DIM_ + col] = (bf16)v;
                }
            }
        }
    }
}

// ---------------- transpose+convert fp32 [R,C] -> bf16 [C,R] -----------------
__global__ void transpose_conv(const float* __restrict__ in, bf16* __restrict__ out,
                               int R, int Cc) {
    __shared__ float t[32][33];
    int c0 = blockIdx.x * 32, r0 = blockIdx.y * 32;
    int tx = threadIdx.x & 31, ty = threadIdx.x >> 5;   // 32 x 8
    #pragma unroll
    for (int i = 0; i < 4; i++) {
        int r = r0 + ty + i * 8;
        if (r < R && c0 + tx < Cc) t[ty + i * 8][tx] = in[(size_t)r * Cc + c0 + tx];
    }
    __syncthreads();
    #pragma unroll
    for (int i = 0; i < 4; i++) {
        int c = c0 + ty + i * 8, r = r0 + tx;
        if (c < Cc && r < R) out[(size_t)c * R + r] = (bf16)t[tx][ty + i * 8];
    }
}

// ---------------- mean-pool over 196 patches: bf16 in -> bf16 out ------------
__global__ void pool_mean(const bf16* __restrict__ x, bf16* __restrict__ pooled) {
    int b = blockIdx.x;
    int d = blockIdx.y * 256 + threadIdx.x;
    const bf16* p = x + (size_t)b * NP_ * DIM_ + d;
    float s = 0.f;
    for (int n = 0; n < NP_; n++) s += (float)p[(size_t)n * DIM_];
    pooled[(size_t)b * DIM_ + d] = (bf16)(s * (1.0f / NP_));
}

// =============================================================================
extern "C" void kernel_launch(void* const* d_in, const int* in_sizes, int n_in,
                              void* d_out, int out_size, void* d_ws, size_t ws_size,
                              hipStream_t stream) {
    const float* image  = (const float*)d_in[0];
    const float* pos    = (const float*)d_in[1];
    const float* ln_p_g = (const float*)d_in[2];
    const float* ln_p_b = (const float*)d_in[3];
    const float* W_emb  = (const float*)d_in[4];
    const float* b_emb  = (const float*)d_in[5];
    const float* ln_e_g = (const float*)d_in[6];
    const float* ln_e_b = (const float*)d_in[7];
    const float* WV     = (const float*)d_in[8];
    const float* WK     = (const float*)d_in[9];
    const float* WQ     = (const float*)d_in[10];
    const float* ln_g   = (const float*)d_in[11];
    const float* ln_b   = (const float*)d_in[12];
    const float* W_last = (const float*)d_in[13];
    const float* b_last = (const float*)d_in[14];
    float* out = (float*)d_out;

    char* p = (char*)d_ws;
    auto alloc = [&](size_t bytes) { char* r = p; p += (bytes + 255) & ~(size_t)255; return r; };
    // x: bf16 residual stream [12544,1024]
    bf16*  x = (bf16*)alloc((size_t)ROWS_ * DIM_ * 2);
    // attention region: S (fp32) | fwT (bf16, rows pitch 224, pad cols zero)
    char*  region = alloc(9834496 + 29360128);
    float* S   = (float*)region;                                // 9,834,496 B
    bf16*  fwT = (bf16*)(region + 9834496);                     // 29,360,128 B
    // ORDER AUDIT (gld staging overruns): S-gemm B-tail reads ≤123 KB past
    // h_bf (into t_bf); S-gemm A-tail ≤123 KB past t_bf (into WembT); fw-gemm
    // B-tail past h_bf (into t_bf); classifier N-tail ≤49 KB past WlastT
    // (into pooled). Keep this order.
    bf16*  h_bf  = (bf16*)alloc((size_t)ROWS_ * DIM_ * 2);
    bf16*  t_bf  = (bf16*)alloc((size_t)ROWS_ * DIM_ * 2);
    bf16*  WembT  = (bf16*)alloc((size_t)DIM_ * PD_ * 2);
    bf16*  WQ_bf  = (bf16*)alloc((size_t)DIM_ * DIM_ * 2);     // untransposed bf16
    bf16*  WK_bf  = (bf16*)alloc((size_t)DIM_ * DIM_ * 2);
    bf16*  WqkT   = (bf16*)alloc((size_t)DIM_ * DIM_ * 2);     // (WQ WK^T)^T = WK WQ^T
    bf16*  WVT    = (bf16*)alloc((size_t)VDIM_ * VDIM_ * 2);
    bf16*  WlastT = (bf16*)alloc((size_t)NC_ * DIM_ * 2);
    bf16*  pooled = (bf16*)alloc((size_t)B_ * DIM_ * 2);

    // --- weight prep, once per call ------------------------------------------
    transpose_conv<<<dim3(32, 24), 256, 0, stream>>>(W_emb,  WembT,  PD_,  DIM_);
    conv_bf16<<<1024, 256, 0, stream>>>(WQ, WQ_bf, (size_t)DIM_ * DIM_ / 4);
    conv_bf16<<<1024, 256, 0, stream>>>(WK, WK_bf, (size_t)DIM_ * DIM_ / 4);
    // WqkT[c,d] = sum_e WK[c,e] * WQ[d,e]   (A=WK_bf, BT=WQ_bf)
    gemm_bt_big<true><<<dim3(8, 8), 256, 0, stream>>>(
        WK_bf, WQ_bf, WqkT, nullptr, DIM_, DIM_, DIM_);
    transpose_conv<<<dim3(4, 4),   256, 0, stream>>>(WV,     WVT,    VDIM_, VDIM_);
    transpose_conv<<<dim3(32, 32), 256, 0, stream>>>(W_last, WlastT, DIM_, NC_);

    // --- stem ----------------------------------------------------------------
    patchify_ln<<<ROWS_, 256, 0, stream>>>(image, ln_p_g, ln_p_b, t_bf);
    gemm_bt_big<true><<<dim3(DIM_ / 128, ROWS_ / 128), 256, 0, stream>>>(
        t_bf, WembT, h_bf, b_emb, ROWS_, DIM_, PD_);
    ln_rows<<<ROWS_, 256, 0, stream>>>(h_bf, x, ln_e_g, ln_e_b, pos);

    // --- zero fwT (29,360,128 B = 1,835,008 float4): pad cols stay zero ------
    zero_f4<<<2048, 256, 0, stream>>>((float4*)fwT, (size_t)29360128 / 16);

    const long XS   = (long)NP_ * DIM_;     // h/t/x per-batch stride
    const long AS   = (long)NP_ * NP_;      // S per-batch stride
    const long FTS  = (long)DIM_ * NPP_;    // fwT per-batch stride
    for (int layer = 0; layer < DEPTH_; layer++) {
        // h = LN(x)
        ln_rows<<<ROWS_, 256, 0, stream>>>(x, h_bf, ln_g, ln_b, nullptr);
        // t = h @ Wqk   (N=1024; folded q,k projections)
        gemm_bt_big<true><<<dim3(DIM_ / 128, ROWS_ / 128), 256, 0, stream>>>(
            h_bf, WqkT, t_bf, nullptr, ROWS_, DIM_, DIM_);
        // S = scale * t @ h^T   (batched over b; 64-tile)
        gemm_bt_small<false><<<dim3(4, 4, B_), 256, 0, stream>>>(
            t_bf, XS, 0, DIM_, h_bf, XS, 0, DIM_, S, AS, 0, NP_,
            nullptr, nullptr, 0, NP_, NP_, DIM_, SCALE_, 1);
        // fwT[b][hd*128+dv][n] = sum_k WVT[dv][k] * h[b][n][hd*128+k];  z=b*8+hd
        gemm_bt_small<true><<<dim3(4, 2, B_ * HEADS_), 256, 0, stream>>>(
            WVT, 0, 0, VDIM_,
            h_bf, XS, VDIM_, DIM_,
            fwT, FTS, (long)VDIM_ * NPP_, NPP_,
            nullptr, nullptr, 0, VDIM_, NP_, VDIM_, 1.0f, HEADS_);
        // x = softmax(S) @ fwT^T + h   (fused, no K-loop barriers)
        attn_pv<<<dim3(4, B_), 256, 0, stream>>>(S, fwT, h_bf, x);
    }

    pool_mean<<<dim3(B_, 4), 256, 0, stream>>>(x, pooled);
    gemm_bt_small<false><<<dim3(16, 1, 1), 256, 0, stream>>>(
        pooled, 0, 0, DIM_, WlastT, 0, 0, DIM_, out, 0, 0, NC_,
        b_last, nullptr, 0, B_, NC_, DIM_, 1.0f, 1);
}

// Round 12
// 1278.809 us; speedup vs baseline: 1.0639x; 1.0639x over previous
//
#include <hip/hip_runtime.h>
#include <stdint.h>

#define B_    64
#define C_    3
#define H_    224
#define W_    224
#define P_    16
#define GH_   14
#define NP_   196
#define NPP_  224          // NP padded to multiple of 32
#define PD_   768
#define HEADS_ 8
#define VDIM_ 128
#define DIM_  1024
#define DEPTH_ 6
#define NC_   1000
#define EPS_  1e-5f
#define SCALE_ 0.08838834764831845f   // 128^-0.5
#define ROWS_ (B_*NP_)                 // 12544

typedef __bf16 bf16;
typedef __bf16 bfv8 __attribute__((ext_vector_type(8)));
typedef __bf16 bfv4 __attribute__((ext_vector_type(4)));
typedef float  f32x4 __attribute__((ext_vector_type(4)));

#define AS1 __attribute__((address_space(1)))
#define AS3 __attribute__((address_space(3)))

__device__ __forceinline__ void gld_lds16(const bf16* g, bf16* l) {
    __builtin_amdgcn_global_load_lds((const AS1 uint32_t*)g, (AS3 uint32_t*)l, 16, 0, 0);
}

__device__ __forceinline__ f32x4 mfma16(bfv8 a, bfv8 b, f32x4 c) {
    return __builtin_amdgcn_mfma_f32_16x16x32_bf16(a, b, c, 0, 0, 0);
}

// ---------------- zero-fill (float4 grid-stride) -----------------------------
__global__ void zero_f4(float4* __restrict__ p, size_t n4) {
    size_t i = (size_t)blockIdx.x * blockDim.x + threadIdx.x;
    size_t stride = (size_t)gridDim.x * blockDim.x;
    float4 z = {0.f, 0.f, 0.f, 0.f};
    for (; i < n4; i += stride) p[i] = z;
}

// ---------------- fp32 -> bf16 elementwise convert (x4 per thread) -----------
__global__ void conv_bf16(const float* __restrict__ in, bf16* __restrict__ out,
                          size_t n4) {
    size_t i = (size_t)blockIdx.x * blockDim.x + threadIdx.x;
    size_t stride = (size_t)gridDim.x * blockDim.x;
    for (; i < n4; i += stride) {
        float4 v = ((const float4*)in)[i];
        bfv4 o = { (bf16)v.x, (bf16)v.y, (bf16)v.z, (bf16)v.w };
        *(bfv4*)(out + i * 4) = o;
    }
}

// ---------------- block-wide twin reduction ---------------------------------
__device__ inline void block_reduce_2(float& a, float& b) {
    __shared__ float sa[4], sb[4];
    #pragma unroll
    for (int o = 32; o > 0; o >>= 1) {
        a += __shfl_down(a, o);
        b += __shfl_down(b, o);
    }
    int lane = threadIdx.x & 63, wid = threadIdx.x >> 6;
    if (lane == 0) { sa[wid] = a; sb[wid] = b; }
    __syncthreads();
    a = sa[0] + sa[1] + sa[2] + sa[3];
    b = sb[0] + sb[1] + sb[2] + sb[3];
    __syncthreads();
}

// ---------------- patchify + LayerNorm over PD=768 -> bf16 -------------------
__global__ void patchify_ln(const float* __restrict__ img,
                            const float* __restrict__ g,
                            const float* __restrict__ beta,
                            bf16* __restrict__ out) {
    int bn = blockIdx.x;
    int b = bn / NP_, n = bn % NP_;
    int gh = n / GH_, gw = n % GH_;
    int t = threadIdx.x;              // pixel 0..255
    int p1 = t >> 4, p2 = t & 15;
    int row = gh * P_ + p1, col = gw * P_ + p2;
    const float* ip = img + (size_t)b * C_ * H_ * W_ + (size_t)row * W_ + col;
    float v0 = ip[0];
    float v1 = ip[H_ * W_];
    float v2 = ip[2 * H_ * W_];
    float s  = v0 + v1 + v2;
    float s2 = v0 * v0 + v1 * v1 + v2 * v2;
    block_reduce_2(s, s2);
    float mean = s * (1.0f / PD_);
    float var  = s2 * (1.0f / PD_) - mean * mean;
    float r = rsqrtf(var + EPS_);
    int d = t * 3;
    bf16* op = out + (size_t)bn * PD_ + d;
    op[0] = (bf16)((v0 - mean) * r * g[d]     + beta[d]);
    op[1] = (bf16)((v1 - mean) * r * g[d + 1] + beta[d + 1]);
    op[2] = (bf16)((v2 - mean) * r * g[d + 2] + beta[d + 2]);
}

// ---------------- row LayerNorm over DIM=1024: bf16 in -> bf16 out -----------
__global__ void ln_rows(const bf16* __restrict__ in,
                        bf16* __restrict__ outb,
                        const float* __restrict__ g, const float* __restrict__ beta,
                        const float* __restrict__ pos) {
    int r = blockIdx.x;
    int t = threadIdx.x;
    bfv4 iv = *(const bfv4*)(in + (size_t)r * DIM_ + (size_t)t * 4);
    float4 v = { (float)iv[0], (float)iv[1], (float)iv[2], (float)iv[3] };
    float s  = v.x + v.y + v.z + v.w;
    float s2 = v.x * v.x + v.y * v.y + v.z * v.z + v.w * v.w;
    block_reduce_2(s, s2);
    float mean = s * (1.0f / DIM_);
    float var  = s2 * (1.0f / DIM_) - mean * mean;
    float rs = rsqrtf(var + EPS_);
    int n = r % NP_;
    float4 gv = ((const float4*)g)[t];
    float4 bv = ((const float4*)beta)[t];
    float4 o;
    o.x = (v.x - mean) * rs * gv.x + bv.x;
    o.y = (v.y - mean) * rs * gv.y + bv.y;
    o.z = (v.z - mean) * rs * gv.z + bv.z;
    o.w = (v.w - mean) * rs * gv.w + bv.w;
    if (pos) {
        float4 pv = ((const float4*)(pos + (size_t)n * DIM_))[t];
        o.x += pv.x; o.y += pv.y; o.z += pv.z; o.w += pv.w;
    }
    bfv4 ob = { (bf16)o.x, (bf16)o.y, (bf16)o.z, (bf16)o.w };
    *(bfv4*)(outb + (size_t)r * DIM_ + (size_t)t * 4) = ob;
}

// ---------------- big MFMA GEMM: 128x128 tile ------------------------------
// requires M%128==0, N%128==0, K%32==0. XCD swizzle: groups of 8 m-tiles.
template<bool OUT_BF16>
__global__ __launch_bounds__(256)
void gemm_bt_big(const bf16* __restrict__ A, const bf16* __restrict__ BT,
                 void* __restrict__ Cout, const float* __restrict__ bias,
                 int M, int N, int K) {
    __shared__ bf16 Asm[128 * 32];
    __shared__ bf16 Bsm[128 * 32];
    const int tid = threadIdx.x;
    const int wave = tid >> 6, lane = tid & 63;
    const int MT = gridDim.y, NT = gridDim.x;
    const int flat = blockIdx.y * NT + blockIdx.x;
    const int per = 8 * NT;
    const int group = flat / per;
    const int within = flat % per;
    int gm = MT - group * 8; if (gm > 8) gm = 8;
    const int m0 = (group * 8 + within % gm) * 128;
    const int n0 = (within / gm) * 128;
    const int r16 = lane >> 2;
    const int kc  = (lane & 3) * 8;
    const bf16* Ag0 = A  + (size_t)(m0 + wave * 16 + r16) * K + kc;
    const bf16* Ag1 = Ag0 + (size_t)64 * K;
    const bf16* Bg0 = BT + (size_t)(n0 + wave * 16 + r16) * K + kc;
    const bf16* Bg1 = Bg0 + (size_t)64 * K;
    bf16* Al0 = Asm + wave * 512;
    bf16* Al1 = Asm + 2048 + wave * 512;
    bf16* Bl0 = Bsm + wave * 512;
    bf16* Bl1 = Bsm + 2048 + wave * 512;
    const int qd = lane >> 4, l15 = lane & 15;
    const int wm = (wave >> 1) * 64, wn = (wave & 1) * 64;
    f32x4 acc[4][4] = {};
    for (int k0 = 0; k0 < K; k0 += 32) {
        gld_lds16(Ag0 + k0, Al0);
        gld_lds16(Ag1 + k0, Al1);
        gld_lds16(Bg0 + k0, Bl0);
        gld_lds16(Bg1 + k0, Bl1);
        __syncthreads();
        bfv8 af[4], bfr[4];
        #pragma unroll
        for (int i = 0; i < 4; i++)
            af[i] = *(const bfv8*)(Asm + (wm + i * 16 + l15) * 32 + qd * 8);
        #pragma unroll
        for (int j = 0; j < 4; j++)
            bfr[j] = *(const bfv8*)(Bsm + (wn + j * 16 + l15) * 32 + qd * 8);
        #pragma unroll
        for (int i = 0; i < 4; i++)
            #pragma unroll
            for (int j = 0; j < 4; j++)
                acc[i][j] = mfma16(af[i], bfr[j], acc[i][j]);
        __syncthreads();
    }
    float* Cf = (float*)Cout;
    bf16*  Cb = (bf16*)Cout;
    #pragma unroll
    for (int i = 0; i < 4; i++) {
        int rowb = m0 + wm + i * 16 + qd * 4;
        #pragma unroll
        for (int j = 0; j < 4; j++) {
            int col = n0 + wn + j * 16 + l15;
            float bv = bias ? bias[col] : 0.0f;
            #pragma unroll
            for (int r = 0; r < 4; r++) {
                float v = acc[i][j][r] + bv;
                if (OUT_BF16) Cb[(size_t)(rowb + r) * N + col] = (bf16)v;
                else          Cf[(size_t)(rowb + r) * N + col] = v;
            }
        }
    }
}

// ---------------- 128x64-tile MFMA GEMM (occupancy-friendly) -----------------
// requires M%128==0, N%64==0, K%32==0. 1568 blocks at [12544,1024] = 6.1/CU
// (vs 784 = 3.06/CU for the 128x128 tile — the t-GEMM tail fix). 8 MFMA/wave
// per K-step. Same gld_lds16 staging + XCD swizzle as gemm_bt_big.
template<bool OUT_BF16>
__global__ __launch_bounds__(256)
void gemm_bt_m128n64(const bf16* __restrict__ A, const bf16* __restrict__ BT,
                     void* __restrict__ Cout, const float* __restrict__ bias,
                     int M, int N, int K) {
    __shared__ bf16 Asm[128 * 32];
    __shared__ bf16 Bsm[64 * 32];
    const int tid = threadIdx.x;
    const int wave = tid >> 6, lane = tid & 63;
    const int MT = gridDim.y, NT = gridDim.x;
    const int flat = blockIdx.y * NT + blockIdx.x;
    const int per = 8 * NT;
    const int group = flat / per;
    const int within = flat % per;
    int gm = MT - group * 8; if (gm > 8) gm = 8;
    const int m0 = (group * 8 + within % gm) * 128;
    const int n0 = (within / gm) * 64;
    const int r16 = lane >> 2;
    const int kc  = (lane & 3) * 8;
    const bf16* Ag0 = A  + (size_t)(m0 + wave * 16 + r16) * K + kc;
    const bf16* Ag1 = Ag0 + (size_t)64 * K;
    const bf16* Bg  = BT + (size_t)(n0 + wave * 16 + r16) * K + kc;
    bf16* Al0 = Asm + wave * 512;
    bf16* Al1 = Asm + 2048 + wave * 512;
    bf16* Bl  = Bsm + wave * 512;
    const int qd = lane >> 4, l15 = lane & 15;
    const int wm = (wave >> 1) * 64, wn = (wave & 1) * 32;
    f32x4 acc[4][2] = {};
    for (int k0 = 0; k0 < K; k0 += 32) {
        gld_lds16(Ag0 + k0, Al0);
        gld_lds16(Ag1 + k0, Al1);
        gld_lds16(Bg  + k0, Bl);
        __syncthreads();
        bfv8 af[4], bfr[2];
        #pragma unroll
        for (int i = 0; i < 4; i++)
            af[i] = *(const bfv8*)(Asm + (wm + i * 16 + l15) * 32 + qd * 8);
        #pragma unroll
        for (int j = 0; j < 2; j++)
            bfr[j] = *(const bfv8*)(Bsm + (wn + j * 16 + l15) * 32 + qd * 8);
        #pragma unroll
        for (int i = 0; i < 4; i++)
            #pragma unroll
            for (int j = 0; j < 2; j++)
                acc[i][j] = mfma16(af[i], bfr[j], acc[i][j]);
        __syncthreads();
    }
    float* Cf = (float*)Cout;
    bf16*  Cb = (bf16*)Cout;
    #pragma unroll
    for (int i = 0; i < 4; i++) {
        int rowb = m0 + wm + i * 16 + qd * 4;
        #pragma unroll
        for (int j = 0; j < 2; j++) {
            int col = n0 + wn + j * 16 + l15;
            float bv = bias ? bias[col] : 0.0f;
            #pragma unroll
            for (int r = 0; r < 4; r++) {
                float v = acc[i][j][r] + bv;
                if (OUT_BF16) Cb[(size_t)(rowb + r) * N + col] = (bf16)v;
                else          Cf[(size_t)(rowb + r) * N + col] = v;
            }
        }
    }
}

// ---------------- small MFMA GEMM: 64x64 tile, 2-level batch -----------------
// gld_lds16 staging: rows beyond M/N read unguarded into adjacent workspace
// (caller-audited). Stores are tail-masked. K%32==0.
template<bool OUT_BF16>
__global__ __launch_bounds__(256)
void gemm_bt_small(const bf16* __restrict__ A, long sA1, long sA2, long lda,
                   const bf16* __restrict__ BT, long sB1, long sB2, long ldb,
                   void* __restrict__ Cout, long sC1, long sC2, long ldc,
                   const float* __restrict__ bias,
                   const bf16* __restrict__ resid, long sR1,
                   int M, int N, int K, float alpha, int zdiv) {
    __shared__ bf16 Asm[64 * 32];
    __shared__ bf16 Bsm[64 * 32];
    const int bz = blockIdx.z;
    const int z1 = bz / zdiv, z2 = bz % zdiv;
    A  += (size_t)z1 * sA1 + (size_t)z2 * sA2;
    BT += (size_t)z1 * sB1 + (size_t)z2 * sB2;
    const int tid = threadIdx.x;
    const int wave = tid >> 6, lane = tid & 63;
    const int m0 = blockIdx.y * 64, n0 = blockIdx.x * 64;
    const int r16 = lane >> 2;
    const int kc  = (lane & 3) * 8;
    const int qd = lane >> 4, l15 = lane & 15;
    const bf16* Ag = A  + (size_t)(m0 + wave * 16 + r16) * lda + kc;
    const bf16* Bg = BT + (size_t)(n0 + wave * 16 + r16) * ldb + kc;
    bf16* Al = Asm + wave * 512;
    bf16* Bl = Bsm + wave * 512;
    f32x4 acc[4] = {};
    for (int k0 = 0; k0 < K; k0 += 32) {
        gld_lds16(Ag + k0, Al);
        gld_lds16(Bg + k0, Bl);
        __syncthreads();
        bfv8 af = *(const bfv8*)(Asm + (wave * 16 + l15) * 32 + qd * 8);
        #pragma unroll
        for (int j = 0; j < 4; j++) {
            bfv8 bv = *(const bfv8*)(Bsm + (j * 16 + l15) * 32 + qd * 8);
            acc[j] = mfma16(af, bv, acc[j]);
        }
        __syncthreads();
    }
    float* Cf = (float*)Cout + (size_t)z1 * sC1 + (size_t)z2 * sC2;
    bf16*  Cb = (bf16*)Cout + (size_t)z1 * sC1 + (size_t)z2 * sC2;
    const bf16* rs = resid ? resid + (size_t)z1 * sR1 : nullptr;
    #pragma unroll
    for (int j = 0; j < 4; j++) {
        int col = n0 + j * 16 + l15;
        if (col >= N) continue;
        float bv = bias ? bias[col] : 0.f;
        #pragma unroll
        for (int r = 0; r < 4; r++) {
            int row = m0 + wave * 16 + qd * 4 + r;
            if (row >= M) continue;
            float v = alpha * acc[j][r] + bv;
            if (rs) v += (float)rs[(size_t)row * ldc + col];
            if (OUT_BF16) Cb[(size_t)row * ldc + col] = (bf16)v;
            else          Cf[(size_t)row * ldc + col] = v;
        }
    }
}

// ------- softmax over rows of 196: fp32 in -> bf16 PADDED out [b][224][224] --
__global__ void softmax196(const float* __restrict__ S, bf16* __restrict__ Apad) {
    __shared__ float red[4];
    int row = blockIdx.x;             // b*196 + n
    int b = row / NP_, n = row % NP_;
    const float* p = S + (size_t)row * NP_;
    int t = threadIdx.x;
    float v = (t < NP_) ? p[t] : -1e30f;
    float m = v;
    #pragma unroll
    for (int o = 32; o > 0; o >>= 1) m = fmaxf(m, __shfl_down(m, o));
    int lane = t & 63, wid = t >> 6;
    if (lane == 0) red[wid] = m;
    __syncthreads();
    m = fmaxf(fmaxf(red[0], red[1]), fmaxf(red[2], red[3]));
    float e = (t < NP_) ? __expf(v - m) : 0.f;
    float s = e;
    #pragma unroll
    for (int o = 32; o > 0; o >>= 1) s += __shfl_down(s, o);
    __syncthreads();
    if (lane == 0) red[wid] = s;
    __syncthreads();
    s = red[0] + red[1] + red[2] + red[3];
    if (t < NPP_) {
        bf16* op = Apad + ((size_t)b * NPP_ + n) * NPP_;
        op[t] = (bf16)((t < NP_) ? (e / s) : 0.f);
    }
}

// ---------------- transpose+convert fp32 [R,C] -> bf16 [C,R] -----------------
__global__ void transpose_conv(const float* __restrict__ in, bf16* __restrict__ out,
                               int R, int Cc) {
    __shared__ float t[32][33];
    int c0 = blockIdx.x * 32, r0 = blockIdx.y * 32;
    int tx = threadIdx.x & 31, ty = threadIdx.x >> 5;   // 32 x 8
    #pragma unroll
    for (int i = 0; i < 4; i++) {
        int r = r0 + ty + i * 8;
        if (r < R && c0 + tx < Cc) t[ty + i * 8][tx] = in[(size_t)r * Cc + c0 + tx];
    }
    __syncthreads();
    #pragma unroll
    for (int i = 0; i < 4; i++) {
        int c = c0 + ty + i * 8, r = r0 + tx;
        if (c < Cc && r < R) out[(size_t)c * R + r] = (bf16)t[tx][ty + i * 8];
    }
}

// ---------------- mean-pool over 196 patches: bf16 in -> bf16 out ------------
__global__ void pool_mean(const bf16* __restrict__ x, bf16* __restrict__ pooled) {
    int b = blockIdx.x;
    int d = blockIdx.y * 256 + threadIdx.x;
    const bf16* p = x + (size_t)b * NP_ * DIM_ + d;
    float s = 0.f;
    for (int n = 0; n < NP_; n++) s += (float)p[(size_t)n * DIM_];
    pooled[(size_t)b * DIM_ + d] = (bf16)(s * (1.0f / NP_));
}

// =============================================================================
extern "C" void kernel_launch(void* const* d_in, const int* in_sizes, int n_in,
                              void* d_out, int out_size, void* d_ws, size_t ws_size,
                              hipStream_t stream) {
    const float* image  = (const float*)d_in[0];
    const float* pos    = (const float*)d_in[1];
    const float* ln_p_g = (const float*)d_in[2];
    const float* ln_p_b = (const float*)d_in[3];
    const float* W_emb  = (const float*)d_in[4];
    const float* b_emb  = (const float*)d_in[5];
    const float* ln_e_g = (const float*)d_in[6];
    const float* ln_e_b = (const float*)d_in[7];
    const float* WV     = (const float*)d_in[8];
    const float* WK     = (const float*)d_in[9];
    const float* WQ     = (const float*)d_in[10];
    const float* ln_g   = (const float*)d_in[11];
    const float* ln_b   = (const float*)d_in[12];
    const float* W_last = (const float*)d_in[13];
    const float* b_last = (const float*)d_in[14];
    float* out = (float*)d_out;

    char* p = (char*)d_ws;
    auto alloc = [&](size_t bytes) { char* r = p; p += (bytes + 255) & ~(size_t)255; return r; };
    // x: bf16 residual stream [12544,1024]
    bf16*  x = (bf16*)alloc((size_t)ROWS_ * DIM_ * 2);
    // attention region: S (fp32) | A_pad | fwT — adjacency required for the
    // A·V staging overrun (A_pad tail -> fwT).
    char*  region = alloc(9834496 + 6422528 + 29360128);
    float* S     = (float*)region;                              // 9,834,496 B
    bf16*  A_pad = (bf16*)(region + 9834496);                   // 6,422,528 B
    bf16*  fwT   = (bf16*)(region + 9834496 + 6422528);         // 29,360,128 B
    // ORDER AUDIT (gld staging overruns): S-gemm B-tail reads ≤123 KB past
    // h_bf (into t_bf); S-gemm A-tail ≤123 KB past t_bf (into WembT); fw-gemm
    // B-tail past h_bf (into t_bf); A·V A-tail ≤27 KB past A_pad (into fwT);
    // classifier N-tail ≤49 KB past WlastT (into pooled). Keep this order.
    bf16*  h_bf  = (bf16*)alloc((size_t)ROWS_ * DIM_ * 2);
    bf16*  t_bf  = (bf16*)alloc((size_t)ROWS_ * DIM_ * 2);
    bf16*  WembT  = (bf16*)alloc((size_t)DIM_ * PD_ * 2);
    bf16*  WQ_bf  = (bf16*)alloc((size_t)DIM_ * DIM_ * 2);     // untransposed bf16
    bf16*  WK_bf  = (bf16*)alloc((size_t)DIM_ * DIM_ * 2);
    bf16*  WqkT   = (bf16*)alloc((size_t)DIM_ * DIM_ * 2);     // (WQ WK^T)^T = WK WQ^T
    bf16*  WVT    = (bf16*)alloc((size_t)VDIM_ * VDIM_ * 2);
    bf16*  WlastT = (bf16*)alloc((size_t)NC_ * DIM_ * 2);
    bf16*  pooled = (bf16*)alloc((size_t)B_ * DIM_ * 2);

    // --- weight prep, once per call ------------------------------------------
    transpose_conv<<<dim3(32, 24), 256, 0, stream>>>(W_emb,  WembT,  PD_,  DIM_);
    conv_bf16<<<1024, 256, 0, stream>>>(WQ, WQ_bf, (size_t)DIM_ * DIM_ / 4);
    conv_bf16<<<1024, 256, 0, stream>>>(WK, WK_bf, (size_t)DIM_ * DIM_ / 4);
    // WqkT[c,d] = sum_e WK[c,e] * WQ[d,e]   (A=WK_bf, BT=WQ_bf)
    gemm_bt_big<true><<<dim3(8, 8), 256, 0, stream>>>(
        WK_bf, WQ_bf, WqkT, nullptr, DIM_, DIM_, DIM_);
    transpose_conv<<<dim3(4, 4),   256, 0, stream>>>(WV,     WVT,    VDIM_, VDIM_);
    transpose_conv<<<dim3(32, 32), 256, 0, stream>>>(W_last, WlastT, DIM_, NC_);

    // --- stem ----------------------------------------------------------------
    patchify_ln<<<ROWS_, 256, 0, stream>>>(image, ln_p_g, ln_p_b, t_bf);
    gemm_bt_big<true><<<dim3(DIM_ / 128, ROWS_ / 128), 256, 0, stream>>>(
        t_bf, WembT, h_bf, b_emb, ROWS_, DIM_, PD_);
    ln_rows<<<ROWS_, 256, 0, stream>>>(h_bf, x, ln_e_g, ln_e_b, pos);

    // --- zero A_pad + fwT (adjacent, 35,782,656 B = 2,236,416 float4) --------
    zero_f4<<<2048, 256, 0, stream>>>((float4*)A_pad, (size_t)35782656 / 16);

    const long XS   = (long)NP_ * DIM_;     // h/t/x per-batch stride
    const long AS   = (long)NP_ * NP_;      // S per-batch stride
    const long APS  = (long)NPP_ * NPP_;    // padded A per-batch stride
    const long FTS  = (long)DIM_ * NPP_;    // fwT per-batch stride
    for (int layer = 0; layer < DEPTH_; layer++) {
        // h = LN(x)
        ln_rows<<<ROWS_, 256, 0, stream>>>(x, h_bf, ln_g, ln_b, nullptr);
        // t = h @ Wqk   (128x64 tiles: 1568 blocks = 6.1/CU)
        gemm_bt_m128n64<true><<<dim3(DIM_ / 64, ROWS_ / 128), 256, 0, stream>>>(
            h_bf, WqkT, t_bf, nullptr, ROWS_, DIM_, DIM_);
        // S = scale * t @ h^T   (batched over b; 64-tile)
        gemm_bt_small<false><<<dim3(4, 4, B_), 256, 0, stream>>>(
            t_bf, XS, 0, DIM_, h_bf, XS, 0, DIM_, S, AS, 0, NP_,
            nullptr, nullptr, 0, NP_, NP_, DIM_, SCALE_, 1);
        // A_pad = softmax(S), cols zero-padded to 224
        softmax196<<<ROWS_, 256, 0, stream>>>(S, A_pad);
        // fwT[b][hd*128+dv][n] = sum_k WVT[dv][k] * h[b][n][hd*128+k];  z=b*8+hd
        gemm_bt_small<true><<<dim3(4, 2, B_ * HEADS_), 256, 0, stream>>>(
            WVT, 0, 0, VDIM_,
            h_bf, XS, VDIM_, DIM_,
            fwT, FTS, (long)VDIM_ * NPP_, NPP_,
            nullptr, nullptr, 0, VDIM_, NP_, VDIM_, 1.0f, HEADS_);
        // x = A_pad @ fwT^T + h   (batched over b; 64-tile, K=224; bf16 out)
        gemm_bt_small<true><<<dim3(16, 4, B_), 256, 0, stream>>>(
            A_pad, APS, 0, NPP_, fwT, FTS, 0, NPP_, x, XS, 0, DIM_,
            nullptr, h_bf, XS, NP_, DIM_, NPP_, 1.0f, 1);
    }

    pool_mean<<<dim3(B_, 4), 256, 0, stream>>>(x, pooled);
    gemm_bt_small<false><<<dim3(16, 1, 1), 256, 0, stream>>>(
        pooled, 0, 0, DIM_, WlastT, 0, 0, DIM_, out, 0, 0, NC_,
        b_last, nullptr, 0, B_, NC_, DIM_, 1.0f, 1);
}

// Round 13
// 1260.159 us; speedup vs baseline: 1.0797x; 1.0148x over previous
//
#include <hip/hip_runtime.h>
#include <stdint.h>

#define B_    64
#define C_    3
#define H_    224
#define W_    224
#define P_    16
#define GH_   14
#define NP_   196
#define NPP_  224          // NP padded to multiple of 32
#define PD_   768
#define HEADS_ 8
#define VDIM_ 128
#define DIM_  1024
#define DEPTH_ 6
#define NC_   1000
#define EPS_  1e-5f
#define SCALE_ 0.08838834764831845f   // 128^-0.5
#define ROWS_ (B_*NP_)                 // 12544

typedef __bf16 bf16;
typedef __bf16 bfv8 __attribute__((ext_vector_type(8)));
typedef __bf16 bfv4 __attribute__((ext_vector_type(4)));
typedef float  f32x4 __attribute__((ext_vector_type(4)));

#define AS1 __attribute__((address_space(1)))
#define AS3 __attribute__((address_space(3)))

__device__ __forceinline__ void gld_lds16(const bf16* g, bf16* l) {
    __builtin_amdgcn_global_load_lds((const AS1 uint32_t*)g, (AS3 uint32_t*)l, 16, 0, 0);
}

__device__ __forceinline__ f32x4 mfma16(bfv8 a, bfv8 b, f32x4 c) {
    return __builtin_amdgcn_mfma_f32_16x16x32_bf16(a, b, c, 0, 0, 0);
}

// LDS bank-conflict-free XOR swizzle (pitch 32 bf16 = 4 chunks of 16B/row):
//   LDS chunk (r, c) holds global chunk (r, c ^ ((r>>1)&3)).
// Store side: lane ℓ (row r=ℓ>>2, lds chunk cl=ℓ&3) sources global chunk
//   cg = cl ^ ((r>>1)&3). Read side: row R chunk q lives at LDS chunk
//   q ^ ((R>>1)&3). Bank window = 16·(R&1) + 4·(q^((R>>1)&3)) → 8 distinct
//   windows per 16 rows → 2-way aliasing = free [m136]. Bit-identical math.
__device__ __forceinline__ int sw_store(int lane) {           // global kc (bf16)
    return (((lane & 3) ^ (((lane >> 2) >> 1) & 3)) * 8);
}
__device__ __forceinline__ int sw_read(int R, int q) {        // LDS off in row (bf16)
    return ((q ^ ((R >> 1) & 3)) * 8);
}

// ---------------- zero-fill (float4 grid-stride) -----------------------------
__global__ void zero_f4(float4* __restrict__ p, size_t n4) {
    size_t i = (size_t)blockIdx.x * blockDim.x + threadIdx.x;
    size_t stride = (size_t)gridDim.x * blockDim.x;
    float4 z = {0.f, 0.f, 0.f, 0.f};
    for (; i < n4; i += stride) p[i] = z;
}

// ---------------- fp32 -> bf16 elementwise convert (x4 per thread) -----------
__global__ void conv_bf16(const float* __restrict__ in, bf16* __restrict__ out,
                          size_t n4) {
    size_t i = (size_t)blockIdx.x * blockDim.x + threadIdx.x;
    size_t stride = (size_t)gridDim.x * blockDim.x;
    for (; i < n4; i += stride) {
        float4 v = ((const float4*)in)[i];
        bfv4 o = { (bf16)v.x, (bf16)v.y, (bf16)v.z, (bf16)v.w };
        *(bfv4*)(out + i * 4) = o;
    }
}

// ---------------- block-wide twin reduction ---------------------------------
__device__ inline void block_reduce_2(float& a, float& b) {
    __shared__ float sa[4], sb[4];
    #pragma unroll
    for (int o = 32; o > 0; o >>= 1) {
        a += __shfl_down(a, o);
        b += __shfl_down(b, o);
    }
    int lane = threadIdx.x & 63, wid = threadIdx.x >> 6;
    if (lane == 0) { sa[wid] = a; sb[wid] = b; }
    __syncthreads();
    a = sa[0] + sa[1] + sa[2] + sa[3];
    b = sb[0] + sb[1] + sb[2] + sb[3];
    __syncthreads();
}

// ---------------- patchify + LayerNorm over PD=768 -> bf16 -------------------
__global__ void patchify_ln(const float* __restrict__ img,
                            const float* __restrict__ g,
                            const float* __restrict__ beta,
                            bf16* __restrict__ out) {
    int bn = blockIdx.x;
    int b = bn / NP_, n = bn % NP_;
    int gh = n / GH_, gw = n % GH_;
    int t = threadIdx.x;              // pixel 0..255
    int p1 = t >> 4, p2 = t & 15;
    int row = gh * P_ + p1, col = gw * P_ + p2;
    const float* ip = img + (size_t)b * C_ * H_ * W_ + (size_t)row * W_ + col;
    float v0 = ip[0];
    float v1 = ip[H_ * W_];
    float v2 = ip[2 * H_ * W_];
    float s  = v0 + v1 + v2;
    float s2 = v0 * v0 + v1 * v1 + v2 * v2;
    block_reduce_2(s, s2);
    float mean = s * (1.0f / PD_);
    float var  = s2 * (1.0f / PD_) - mean * mean;
    float r = rsqrtf(var + EPS_);
    int d = t * 3;
    bf16* op = out + (size_t)bn * PD_ + d;
    op[0] = (bf16)((v0 - mean) * r * g[d]     + beta[d]);
    op[1] = (bf16)((v1 - mean) * r * g[d + 1] + beta[d + 1]);
    op[2] = (bf16)((v2 - mean) * r * g[d + 2] + beta[d + 2]);
}

// ---------------- row LayerNorm over DIM=1024: bf16 in -> bf16 out -----------
__global__ void ln_rows(const bf16* __restrict__ in,
                        bf16* __restrict__ outb,
                        const float* __restrict__ g, const float* __restrict__ beta,
                        const float* __restrict__ pos) {
    int r = blockIdx.x;
    int t = threadIdx.x;
    bfv4 iv = *(const bfv4*)(in + (size_t)r * DIM_ + (size_t)t * 4);
    float4 v = { (float)iv[0], (float)iv[1], (float)iv[2], (float)iv[3] };
    float s  = v.x + v.y + v.z + v.w;
    float s2 = v.x * v.x + v.y * v.y + v.z * v.z + v.w * v.w;
    block_reduce_2(s, s2);
    float mean = s * (1.0f / DIM_);
    float var  = s2 * (1.0f / DIM_) - mean * mean;
    float rs = rsqrtf(var + EPS_);
    int n = r % NP_;
    float4 gv = ((const float4*)g)[t];
    float4 bv = ((const float4*)beta)[t];
    float4 o;
    o.x = (v.x - mean) * rs * gv.x + bv.x;
    o.y = (v.y - mean) * rs * gv.y + bv.y;
    o.z = (v.z - mean) * rs * gv.z + bv.z;
    o.w = (v.w - mean) * rs * gv.w + bv.w;
    if (pos) {
        float4 pv = ((const float4*)(pos + (size_t)n * DIM_))[t];
        o.x += pv.x; o.y += pv.y; o.z += pv.z; o.w += pv.w;
    }
    bfv4 ob = { (bf16)o.x, (bf16)o.y, (bf16)o.z, (bf16)o.w };
    *(bfv4*)(outb + (size_t)r * DIM_ + (size_t)t * 4) = ob;
}

// ---------------- big MFMA GEMM: 128x128 tile, swizzled LDS ------------------
// requires M%128==0, N%128==0, K%32==0. XCD swizzle: groups of 8 m-tiles.
template<bool OUT_BF16>
__global__ __launch_bounds__(256)
void gemm_bt_big(const bf16* __restrict__ A, const bf16* __restrict__ BT,
                 void* __restrict__ Cout, const float* __restrict__ bias,
                 int M, int N, int K) {
    __shared__ bf16 Asm[128 * 32];
    __shared__ bf16 Bsm[128 * 32];
    const int tid = threadIdx.x;
    const int wave = tid >> 6, lane = tid & 63;
    const int MT = gridDim.y, NT = gridDim.x;
    const int flat = blockIdx.y * NT + blockIdx.x;
    const int per = 8 * NT;
    const int group = flat / per;
    const int within = flat % per;
    int gm = MT - group * 8; if (gm > 8) gm = 8;
    const int m0 = (group * 8 + within % gm) * 128;
    const int n0 = (within / gm) * 128;
    const int r16 = lane >> 2;
    const int kc  = sw_store(lane);
    const bf16* Ag0 = A  + (size_t)(m0 + wave * 16 + r16) * K + kc;
    const bf16* Ag1 = Ag0 + (size_t)64 * K;
    const bf16* Bg0 = BT + (size_t)(n0 + wave * 16 + r16) * K + kc;
    const bf16* Bg1 = Bg0 + (size_t)64 * K;
    bf16* Al0 = Asm + wave * 512;
    bf16* Al1 = Asm + 2048 + wave * 512;
    bf16* Bl0 = Bsm + wave * 512;
    bf16* Bl1 = Bsm + 2048 + wave * 512;
    const int qd = lane >> 4, l15 = lane & 15;
    const int wm = (wave >> 1) * 64, wn = (wave & 1) * 64;
    f32x4 acc[4][4] = {};
    for (int k0 = 0; k0 < K; k0 += 32) {
        gld_lds16(Ag0 + k0, Al0);
        gld_lds16(Ag1 + k0, Al1);
        gld_lds16(Bg0 + k0, Bl0);
        gld_lds16(Bg1 + k0, Bl1);
        __syncthreads();
        bfv8 af[4], bfr[4];
        #pragma unroll
        for (int i = 0; i < 4; i++) {
            int R = wm + i * 16 + l15;
            af[i] = *(const bfv8*)(Asm + R * 32 + sw_read(R, qd));
        }
        #pragma unroll
        for (int j = 0; j < 4; j++) {
            int R = wn + j * 16 + l15;
            bfr[j] = *(const bfv8*)(Bsm + R * 32 + sw_read(R, qd));
        }
        #pragma unroll
        for (int i = 0; i < 4; i++)
            #pragma unroll
            for (int j = 0; j < 4; j++)
                acc[i][j] = mfma16(af[i], bfr[j], acc[i][j]);
        __syncthreads();
    }
    float* Cf = (float*)Cout;
    bf16*  Cb = (bf16*)Cout;
    #pragma unroll
    for (int i = 0; i < 4; i++) {
        int rowb = m0 + wm + i * 16 + qd * 4;
        #pragma unroll
        for (int j = 0; j < 4; j++) {
            int col = n0 + wn + j * 16 + l15;
            float bv = bias ? bias[col] : 0.0f;
            #pragma unroll
            for (int r = 0; r < 4; r++) {
                float v = acc[i][j][r] + bv;
                if (OUT_BF16) Cb[(size_t)(rowb + r) * N + col] = (bf16)v;
                else          Cf[(size_t)(rowb + r) * N + col] = v;
            }
        }
    }
}

// ---------------- 128x64-tile MFMA GEMM, swizzled LDS ------------------------
// requires M%128==0, N%64==0, K%32==0. 1568 blocks at [12544,1024] = 6.1/CU.
template<bool OUT_BF16>
__global__ __launch_bounds__(256)
void gemm_bt_m128n64(const bf16* __restrict__ A, const bf16* __restrict__ BT,
                     void* __restrict__ Cout, const float* __restrict__ bias,
                     int M, int N, int K) {
    __shared__ bf16 Asm[128 * 32];
    __shared__ bf16 Bsm[64 * 32];
    const int tid = threadIdx.x;
    const int wave = tid >> 6, lane = tid & 63;
    const int MT = gridDim.y, NT = gridDim.x;
    const int flat = blockIdx.y * NT + blockIdx.x;
    const int per = 8 * NT;
    const int group = flat / per;
    const int within = flat % per;
    int gm = MT - group * 8; if (gm > 8) gm = 8;
    const int m0 = (group * 8 + within % gm) * 128;
    const int n0 = (within / gm) * 64;
    const int r16 = lane >> 2;
    const int kc  = sw_store(lane);
    const bf16* Ag0 = A  + (size_t)(m0 + wave * 16 + r16) * K + kc;
    const bf16* Ag1 = Ag0 + (size_t)64 * K;
    const bf16* Bg  = BT + (size_t)(n0 + wave * 16 + r16) * K + kc;
    bf16* Al0 = Asm + wave * 512;
    bf16* Al1 = Asm + 2048 + wave * 512;
    bf16* Bl  = Bsm + wave * 512;
    const int qd = lane >> 4, l15 = lane & 15;
    const int wm = (wave >> 1) * 64, wn = (wave & 1) * 32;
    f32x4 acc[4][2] = {};
    for (int k0 = 0; k0 < K; k0 += 32) {
        gld_lds16(Ag0 + k0, Al0);
        gld_lds16(Ag1 + k0, Al1);
        gld_lds16(Bg  + k0, Bl);
        __syncthreads();
        bfv8 af[4], bfr[2];
        #pragma unroll
        for (int i = 0; i < 4; i++) {
            int R = wm + i * 16 + l15;
            af[i] = *(const bfv8*)(Asm + R * 32 + sw_read(R, qd));
        }
        #pragma unroll
        for (int j = 0; j < 2; j++) {
            int R = wn + j * 16 + l15;
            bfr[j] = *(const bfv8*)(Bsm + R * 32 + sw_read(R, qd));
        }
        #pragma unroll
        for (int i = 0; i < 4; i++)
            #pragma unroll
            for (int j = 0; j < 2; j++)
                acc[i][j] = mfma16(af[i], bfr[j], acc[i][j]);
        __syncthreads();
    }
    float* Cf = (float*)Cout;
    bf16*  Cb = (bf16*)Cout;
    #pragma unroll
    for (int i = 0; i < 4; i++) {
        int rowb = m0 + wm + i * 16 + qd * 4;
        #pragma unroll
        for (int j = 0; j < 2; j++) {
            int col = n0 + wn + j * 16 + l15;
            float bv = bias ? bias[col] : 0.0f;
            #pragma unroll
            for (int r = 0; r < 4; r++) {
                float v = acc[i][j][r] + bv;
                if (OUT_BF16) Cb[(size_t)(rowb + r) * N + col] = (bf16)v;
                else          Cf[(size_t)(rowb + r) * N + col] = v;
            }
        }
    }
}

// ---------------- small MFMA GEMM: 64x64 tile, 2-level batch, swizzled -------
// gld_lds16 staging: rows beyond M/N read unguarded into adjacent workspace
// (caller-audited). Stores are tail-masked. K%32==0.
template<bool OUT_BF16>
__global__ __launch_bounds__(256)
void gemm_bt_small(const bf16* __restrict__ A, long sA1, long sA2, long lda,
                   const bf16* __restrict__ BT, long sB1, long sB2, long ldb,
                   void* __restrict__ Cout, long sC1, long sC2, long ldc,
                   const float* __restrict__ bias,
                   const bf16* __restrict__ resid, long sR1,
                   int M, int N, int K, float alpha, int zdiv) {
    __shared__ bf16 Asm[64 * 32];
    __shared__ bf16 Bsm[64 * 32];
    const int bz = blockIdx.z;
    const int z1 = bz / zdiv, z2 = bz % zdiv;
    A  += (size_t)z1 * sA1 + (size_t)z2 * sA2;
    BT += (size_t)z1 * sB1 + (size_t)z2 * sB2;
    const int tid = threadIdx.x;
    const int wave = tid >> 6, lane = tid & 63;
    const int m0 = blockIdx.y * 64, n0 = blockIdx.x * 64;
    const int r16 = lane >> 2;
    const int kc  = sw_store(lane);
    const int qd = lane >> 4, l15 = lane & 15;
    const bf16* Ag = A  + (size_t)(m0 + wave * 16 + r16) * lda + kc;
    const bf16* Bg = BT + (size_t)(n0 + wave * 16 + r16) * ldb + kc;
    bf16* Al = Asm + wave * 512;
    bf16* Bl = Bsm + wave * 512;
    f32x4 acc[4] = {};
    for (int k0 = 0; k0 < K; k0 += 32) {
        gld_lds16(Ag + k0, Al);
        gld_lds16(Bg + k0, Bl);
        __syncthreads();
        int RA = wave * 16 + l15;
        bfv8 af = *(const bfv8*)(Asm + RA * 32 + sw_read(RA, qd));
        #pragma unroll
        for (int j = 0; j < 4; j++) {
            int R = j * 16 + l15;
            bfv8 bv = *(const bfv8*)(Bsm + R * 32 + sw_read(R, qd));
            acc[j] = mfma16(af, bv, acc[j]);
        }
        __syncthreads();
    }
    float* Cf = (float*)Cout + (size_t)z1 * sC1 + (size_t)z2 * sC2;
    bf16*  Cb = (bf16*)Cout + (size_t)z1 * sC1 + (size_t)z2 * sC2;
    const bf16* rs = resid ? resid + (size_t)z1 * sR1 : nullptr;
    #pragma unroll
    for (int j = 0; j < 4; j++) {
        int col = n0 + j * 16 + l15;
        if (col >= N) continue;
        float bv = bias ? bias[col] : 0.f;
        #pragma unroll
        for (int r = 0; r < 4; r++) {
            int row = m0 + wave * 16 + qd * 4 + r;
            if (row >= M) continue;
            float v = alpha * acc[j][r] + bv;
            if (rs) v += (float)rs[(size_t)row * ldc + col];
            if (OUT_BF16) Cb[(size_t)row * ldc + col] = (bf16)v;
            else          Cf[(size_t)row * ldc + col] = v;
        }
    }
}

// ------- softmax over rows of 196: fp32 in -> bf16 PADDED out [b][224][224] --
__global__ void softmax196(const float* __restrict__ S, bf16* __restrict__ Apad) {
    __shared__ float red[4];
    int row = blockIdx.x;             // b*196 + n
    int b = row / NP_, n = row % NP_;
    const float* p = S + (size_t)row * NP_;
    int t = threadIdx.x;
    float v = (t < NP_) ? p[t] : -1e30f;
    float m = v;
    #pragma unroll
    for (int o = 32; o > 0; o >>= 1) m = fmaxf(m, __shfl_down(m, o));
    int lane = t & 63, wid = t >> 6;
    if (lane == 0) red[wid] = m;
    __syncthreads();
    m = fmaxf(fmaxf(red[0], red[1]), fmaxf(red[2], red[3]));
    float e = (t < NP_) ? __expf(v - m) : 0.f;
    float s = e;
    #pragma unroll
    for (int o = 32; o > 0; o >>= 1) s += __shfl_down(s, o);
    __syncthreads();
    if (lane == 0) red[wid] = s;
    __syncthreads();
    s = red[0] + red[1] + red[2] + red[3];
    if (t < NPP_) {
        bf16* op = Apad + ((size_t)b * NPP_ + n) * NPP_;
        op[t] = (bf16)((t < NP_) ? (e / s) : 0.f);
    }
}

// ---------------- transpose+convert fp32 [R,C] -> bf16 [C,R] -----------------
__global__ void transpose_conv(const float* __restrict__ in, bf16* __restrict__ out,
                               int R, int Cc) {
    __shared__ float t[32][33];
    int c0 = blockIdx.x * 32, r0 = blockIdx.y * 32;
    int tx = threadIdx.x & 31, ty = threadIdx.x >> 5;   // 32 x 8
    #pragma unroll
    for (int i = 0; i < 4; i++) {
        int r = r0 + ty + i * 8;
        if (r < R && c0 + tx < Cc) t[ty + i * 8][tx] = in[(size_t)r * Cc + c0 + tx];
    }
    __syncthreads();
    #pragma unroll
    for (int i = 0; i < 4; i++) {
        int c = c0 + ty + i * 8, r = r0 + tx;
        if (c < Cc && r < R) out[(size_t)c * R + r] = (bf16)t[tx][ty + i * 8];
    }
}

// ---------------- mean-pool over 196 patches: bf16 in -> bf16 out ------------
__global__ void pool_mean(const bf16* __restrict__ x, bf16* __restrict__ pooled) {
    int b = blockIdx.x;
    int d = blockIdx.y * 256 + threadIdx.x;
    const bf16* p = x + (size_t)b * NP_ * DIM_ + d;
    float s = 0.f;
    for (int n = 0; n < NP_; n++) s += (float)p[(size_t)n * DIM_];
    pooled[(size_t)b * DIM_ + d] = (bf16)(s * (1.0f / NP_));
}

// =============================================================================
extern "C" void kernel_launch(void* const* d_in, const int* in_sizes, int n_in,
                              void* d_out, int out_size, void* d_ws, size_t ws_size,
                              hipStream_t stream) {
    const float* image  = (const float*)d_in[0];
    const float* pos    = (const float*)d_in[1];
    const float* ln_p_g = (const float*)d_in[2];
    const float* ln_p_b = (const float*)d_in[3];
    const float* W_emb  = (const float*)d_in[4];
    const float* b_emb  = (const float*)d_in[5];
    const float* ln_e_g = (const float*)d_in[6];
    const float* ln_e_b = (const float*)d_in[7];
    const float* WV     = (const float*)d_in[8];
    const float* WK     = (const float*)d_in[9];
    const float* WQ     = (const float*)d_in[10];
    const float* ln_g   = (const float*)d_in[11];
    const float* ln_b   = (const float*)d_in[12];
    const float* W_last = (const float*)d_in[13];
    const float* b_last = (const float*)d_in[14];
    float* out = (float*)d_out;

    char* p = (char*)d_ws;
    auto alloc = [&](size_t bytes) { char* r = p; p += (bytes + 255) & ~(size_t)255; return r; };
    // x: bf16 residual stream [12544,1024]
    bf16*  x = (bf16*)alloc((size_t)ROWS_ * DIM_ * 2);
    // attention region: S (fp32) | A_pad | fwT — adjacency required for the
    // A·V staging overrun (A_pad tail -> fwT).
    char*  region = alloc(9834496 + 6422528 + 29360128);
    float* S     = (float*)region;                              // 9,834,496 B
    bf16*  A_pad = (bf16*)(region + 9834496);                   // 6,422,528 B
    bf16*  fwT   = (bf16*)(region + 9834496 + 6422528);         // 29,360,128 B
    // ORDER AUDIT (gld staging overruns): S-gemm B-tail reads ≤123 KB past
    // h_bf (into t_bf); S-gemm A-tail ≤123 KB past t_bf (into WembT); fw-gemm
    // B-tail past h_bf (into t_bf); A·V A-tail ≤27 KB past A_pad (into fwT);
    // classifier N-tail ≤49 KB past WlastT (into pooled). Keep this order.
    bf16*  h_bf  = (bf16*)alloc((size_t)ROWS_ * DIM_ * 2);
    bf16*  t_bf  = (bf16*)alloc((size_t)ROWS_ * DIM_ * 2);
    bf16*  WembT  = (bf16*)alloc((size_t)DIM_ * PD_ * 2);
    bf16*  WQ_bf  = (bf16*)alloc((size_t)DIM_ * DIM_ * 2);     // untransposed bf16
    bf16*  WK_bf  = (bf16*)alloc((size_t)DIM_ * DIM_ * 2);
    bf16*  WqkT   = (bf16*)alloc((size_t)DIM_ * DIM_ * 2);     // (WQ WK^T)^T = WK WQ^T
    bf16*  WVT    = (bf16*)alloc((size_t)VDIM_ * VDIM_ * 2);
    bf16*  WlastT = (bf16*)alloc((size_t)NC_ * DIM_ * 2);
    bf16*  pooled = (bf16*)alloc((size_t)B_ * DIM_ * 2);

    // --- weight prep, once per call ------------------------------------------
    transpose_conv<<<dim3(32, 24), 256, 0, stream>>>(W_emb,  WembT,  PD_,  DIM_);
    conv_bf16<<<1024, 256, 0, stream>>>(WQ, WQ_bf, (size_t)DIM_ * DIM_ / 4);
    conv_bf16<<<1024, 256, 0, stream>>>(WK, WK_bf, (size_t)DIM_ * DIM_ / 4);
    // WqkT[c,d] = sum_e WK[c,e] * WQ[d,e]   (A=WK_bf, BT=WQ_bf)
    gemm_bt_big<true><<<dim3(8, 8), 256, 0, stream>>>(
        WK_bf, WQ_bf, WqkT, nullptr, DIM_, DIM_, DIM_);
    transpose_conv<<<dim3(4, 4),   256, 0, stream>>>(WV,     WVT,    VDIM_, VDIM_);
    transpose_conv<<<dim3(32, 32), 256, 0, stream>>>(W_last, WlastT, DIM_, NC_);

    // --- stem ----------------------------------------------------------------
    patchify_ln<<<ROWS_, 256, 0, stream>>>(image, ln_p_g, ln_p_b, t_bf);
    gemm_bt_big<true><<<dim3(DIM_ / 128, ROWS_ / 128), 256, 0, stream>>>(
        t_bf, WembT, h_bf, b_emb, ROWS_, DIM_, PD_);
    ln_rows<<<ROWS_, 256, 0, stream>>>(h_bf, x, ln_e_g, ln_e_b, pos);

    // --- zero A_pad + fwT (adjacent, 35,782,656 B = 2,236,416 float4) --------
    zero_f4<<<2048, 256, 0, stream>>>((float4*)A_pad, (size_t)35782656 / 16);

    const long XS   = (long)NP_ * DIM_;     // h/t/x per-batch stride
    const long AS   = (long)NP_ * NP_;      // S per-batch stride
    const long APS  = (long)NPP_ * NPP_;    // padded A per-batch stride
    const long FTS  = (long)DIM_ * NPP_;    // fwT per-batch stride
    for (int layer = 0; layer < DEPTH_; layer++) {
        // h = LN(x)
        ln_rows<<<ROWS_, 256, 0, stream>>>(x, h_bf, ln_g, ln_b, nullptr);
        // t = h @ Wqk   (128x64 tiles: 1568 blocks = 6.1/CU)
        gemm_bt_m128n64<true><<<dim3(DIM_ / 64, ROWS_ / 128), 256, 0, stream>>>(
            h_bf, WqkT, t_bf, nullptr, ROWS_, DIM_, DIM_);
        // S = scale * t @ h^T   (batched over b; 64-tile)
        gemm_bt_small<false><<<dim3(4, 4, B_), 256, 0, stream>>>(
            t_bf, XS, 0, DIM_, h_bf, XS, 0, DIM_, S, AS, 0, NP_,
            nullptr, nullptr, 0, NP_, NP_, DIM_, SCALE_, 1);
        // A_pad = softmax(S), cols zero-padded to 224
        softmax196<<<ROWS_, 256, 0, stream>>>(S, A_pad);
        // fwT[b][hd*128+dv][n] = sum_k WVT[dv][k] * h[b][n][hd*128+k];  z=b*8+hd
        gemm_bt_small<true><<<dim3(4, 2, B_ * HEADS_), 256, 0, stream>>>(
            WVT, 0, 0, VDIM_,
            h_bf, XS, VDIM_, DIM_,
            fwT, FTS, (long)VDIM_ * NPP_, NPP_,
            nullptr, nullptr, 0, VDIM_, NP_, VDIM_, 1.0f, HEADS_);
        // x = A_pad @ fwT^T + h   (batched over b; 64-tile, K=224; bf16 out)
        gemm_bt_small<true><<<dim3(16, 4, B_), 256, 0, stream>>>(
            A_pad, APS, 0, NPP_, fwT, FTS, 0, NPP_, x, XS, 0, DIM_,
            nullptr, h_bf, XS, NP_, DIM_, NPP_, 1.0f, 1);
    }

    pool_mean<<<dim3(B_, 4), 256, 0, stream>>>(x, pooled);
    gemm_bt_small<false><<<dim3(16, 1, 1), 256, 0, stream>>>(
        pooled, 0, 0, DIM_, WlastT, 0, 0, DIM_, out, 0, 0, NC_,
        b_last, nullptr, 0, B_, NC_, DIM_, 1.0f, 1);
}

// Round 14
// 1244.666 us; speedup vs baseline: 1.0931x; 1.0124x over previous
//
#include <hip/hip_runtime.h>
#include <stdint.h>

#define B_    64
#define C_    3
#define H_    224
#define W_    224
#define P_    16
#define GH_   14
#define NP_   196
#define NPP_  224          // NP padded to multiple of 32
#define PD_   768
#define HEADS_ 8
#define VDIM_ 128
#define DIM_  1024
#define DEPTH_ 6
#define NC_   1000
#define EPS_  1e-5f
#define SCALE_ 0.08838834764831845f   // 128^-0.5
#define ROWS_ (B_*NP_)                 // 12544

typedef __bf16 bf16;
typedef __bf16 bfv8 __attribute__((ext_vector_type(8)));
typedef __bf16 bfv4 __attribute__((ext_vector_type(4)));
typedef float  f32x4 __attribute__((ext_vector_type(4)));

#define AS1 __attribute__((address_space(1)))
#define AS3 __attribute__((address_space(3)))

__device__ __forceinline__ void gld_lds16(const bf16* g, bf16* l) {
    __builtin_amdgcn_global_load_lds((const AS1 uint32_t*)g, (AS3 uint32_t*)l, 16, 0, 0);
}

__device__ __forceinline__ f32x4 mfma16(bfv8 a, bfv8 b, f32x4 c) {
    return __builtin_amdgcn_mfma_f32_16x16x32_bf16(a, b, c, 0, 0, 0);
}

// LDS bank-conflict-free XOR swizzle, pitch 32 bf16 (4 chunks of 16B/row):
//   LDS chunk (r, c) holds global chunk (r, c ^ ((r>>1)&3)). 2-way = free.
__device__ __forceinline__ int sw_store(int lane) {           // global kc (bf16)
    return (((lane & 3) ^ (((lane >> 2) >> 1) & 3)) * 8);
}
__device__ __forceinline__ int sw_read(int R, int q) {        // LDS off in row (bf16)
    return ((q ^ ((R >> 1) & 3)) * 8);
}

// ---------------- zero-fill (float4 grid-stride) -----------------------------
__global__ void zero_f4(float4* __restrict__ p, size_t n4) {
    size_t i = (size_t)blockIdx.x * blockDim.x + threadIdx.x;
    size_t stride = (size_t)gridDim.x * blockDim.x;
    float4 z = {0.f, 0.f, 0.f, 0.f};
    for (; i < n4; i += stride) p[i] = z;
}

// ---------------- fp32 -> bf16 elementwise convert (x4 per thread) -----------
__global__ void conv_bf16(const float* __restrict__ in, bf16* __restrict__ out,
                          size_t n4) {
    size_t i = (size_t)blockIdx.x * blockDim.x + threadIdx.x;
    size_t stride = (size_t)gridDim.x * blockDim.x;
    for (; i < n4; i += stride) {
        float4 v = ((const float4*)in)[i];
        bfv4 o = { (bf16)v.x, (bf16)v.y, (bf16)v.z, (bf16)v.w };
        *(bfv4*)(out + i * 4) = o;
    }
}

// ---------------- block-wide twin reduction ---------------------------------
__device__ inline void block_reduce_2(float& a, float& b) {
    __shared__ float sa[4], sb[4];
    #pragma unroll
    for (int o = 32; o > 0; o >>= 1) {
        a += __shfl_down(a, o);
        b += __shfl_down(b, o);
    }
    int lane = threadIdx.x & 63, wid = threadIdx.x >> 6;
    if (lane == 0) { sa[wid] = a; sb[wid] = b; }
    __syncthreads();
    a = sa[0] + sa[1] + sa[2] + sa[3];
    b = sb[0] + sb[1] + sb[2] + sb[3];
    __syncthreads();
}

// ---------------- patchify + LayerNorm over PD=768 -> bf16 -------------------
__global__ void patchify_ln(const float* __restrict__ img,
                            const float* __restrict__ g,
                            const float* __restrict__ beta,
                            bf16* __restrict__ out) {
    int bn = blockIdx.x;
    int b = bn / NP_, n = bn % NP_;
    int gh = n / GH_, gw = n % GH_;
    int t = threadIdx.x;              // pixel 0..255
    int p1 = t >> 4, p2 = t & 15;
    int row = gh * P_ + p1, col = gw * P_ + p2;
    const float* ip = img + (size_t)b * C_ * H_ * W_ + (size_t)row * W_ + col;
    float v0 = ip[0];
    float v1 = ip[H_ * W_];
    float v2 = ip[2 * H_ * W_];
    float s  = v0 + v1 + v2;
    float s2 = v0 * v0 + v1 * v1 + v2 * v2;
    block_reduce_2(s, s2);
    float mean = s * (1.0f / PD_);
    float var  = s2 * (1.0f / PD_) - mean * mean;
    float r = rsqrtf(var + EPS_);
    int d = t * 3;
    bf16* op = out + (size_t)bn * PD_ + d;
    op[0] = (bf16)((v0 - mean) * r * g[d]     + beta[d]);
    op[1] = (bf16)((v1 - mean) * r * g[d + 1] + beta[d + 1]);
    op[2] = (bf16)((v2 - mean) * r * g[d + 2] + beta[d + 2]);
}

// ---------------- row LayerNorm over DIM=1024: bf16 in -> bf16 out -----------
__global__ void ln_rows(const bf16* __restrict__ in,
                        bf16* __restrict__ outb,
                        const float* __restrict__ g, const float* __restrict__ beta,
                        const float* __restrict__ pos) {
    int r = blockIdx.x;
    int t = threadIdx.x;
    bfv4 iv = *(const bfv4*)(in + (size_t)r * DIM_ + (size_t)t * 4);
    float4 v = { (float)iv[0], (float)iv[1], (float)iv[2], (float)iv[3] };
    float s  = v.x + v.y + v.z + v.w;
    float s2 = v.x * v.x + v.y * v.y + v.z * v.z + v.w * v.w;
    block_reduce_2(s, s2);
    float mean = s * (1.0f / DIM_);
    float var  = s2 * (1.0f / DIM_) - mean * mean;
    float rs = rsqrtf(var + EPS_);
    int n = r % NP_;
    float4 gv = ((const float4*)g)[t];
    float4 bv = ((const float4*)beta)[t];
    float4 o;
    o.x = (v.x - mean) * rs * gv.x + bv.x;
    o.y = (v.y - mean) * rs * gv.y + bv.y;
    o.z = (v.z - mean) * rs * gv.z + bv.z;
    o.w = (v.w - mean) * rs * gv.w + bv.w;
    if (pos) {
        float4 pv = ((const float4*)(pos + (size_t)n * DIM_))[t];
        o.x += pv.x; o.y += pv.y; o.z += pv.z; o.w += pv.w;
    }
    bfv4 ob = { (bf16)o.x, (bf16)o.y, (bf16)o.z, (bf16)o.w };
    *(bfv4*)(outb + (size_t)r * DIM_ + (size_t)t * 4) = ob;
}

// ---------------- big MFMA GEMM: 128x128 tile, swizzled LDS ------------------
// requires M%128==0, N%128==0, K%32==0. XCD swizzle: groups of 8 m-tiles.
template<bool OUT_BF16>
__global__ __launch_bounds__(256)
void gemm_bt_big(const bf16* __restrict__ A, const bf16* __restrict__ BT,
                 void* __restrict__ Cout, const float* __restrict__ bias,
                 int M, int N, int K) {
    __shared__ bf16 Asm[128 * 32];
    __shared__ bf16 Bsm[128 * 32];
    const int tid = threadIdx.x;
    const int wave = tid >> 6, lane = tid & 63;
    const int MT = gridDim.y, NT = gridDim.x;
    const int flat = blockIdx.y * NT + blockIdx.x;
    const int per = 8 * NT;
    const int group = flat / per;
    const int within = flat % per;
    int gm = MT - group * 8; if (gm > 8) gm = 8;
    const int m0 = (group * 8 + within % gm) * 128;
    const int n0 = (within / gm) * 128;
    const int r16 = lane >> 2;
    const int kc  = sw_store(lane);
    const bf16* Ag0 = A  + (size_t)(m0 + wave * 16 + r16) * K + kc;
    const bf16* Ag1 = Ag0 + (size_t)64 * K;
    const bf16* Bg0 = BT + (size_t)(n0 + wave * 16 + r16) * K + kc;
    const bf16* Bg1 = Bg0 + (size_t)64 * K;
    bf16* Al0 = Asm + wave * 512;
    bf16* Al1 = Asm + 2048 + wave * 512;
    bf16* Bl0 = Bsm + wave * 512;
    bf16* Bl1 = Bsm + 2048 + wave * 512;
    const int qd = lane >> 4, l15 = lane & 15;
    const int wm = (wave >> 1) * 64, wn = (wave & 1) * 64;
    f32x4 acc[4][4] = {};
    for (int k0 = 0; k0 < K; k0 += 32) {
        gld_lds16(Ag0 + k0, Al0);
        gld_lds16(Ag1 + k0, Al1);
        gld_lds16(Bg0 + k0, Bl0);
        gld_lds16(Bg1 + k0, Bl1);
        __syncthreads();
        bfv8 af[4], bfr[4];
        #pragma unroll
        for (int i = 0; i < 4; i++) {
            int R = wm + i * 16 + l15;
            af[i] = *(const bfv8*)(Asm + R * 32 + sw_read(R, qd));
        }
        #pragma unroll
        for (int j = 0; j < 4; j++) {
            int R = wn + j * 16 + l15;
            bfr[j] = *(const bfv8*)(Bsm + R * 32 + sw_read(R, qd));
        }
        #pragma unroll
        for (int i = 0; i < 4; i++)
            #pragma unroll
            for (int j = 0; j < 4; j++)
                acc[i][j] = mfma16(af[i], bfr[j], acc[i][j]);
        __syncthreads();
    }
    float* Cf = (float*)Cout;
    bf16*  Cb = (bf16*)Cout;
    #pragma unroll
    for (int i = 0; i < 4; i++) {
        int rowb = m0 + wm + i * 16 + qd * 4;
        #pragma unroll
        for (int j = 0; j < 4; j++) {
            int col = n0 + wn + j * 16 + l15;
            float bv = bias ? bias[col] : 0.0f;
            #pragma unroll
            for (int r = 0; r < 4; r++) {
                float v = acc[i][j][r] + bv;
                if (OUT_BF16) Cb[(size_t)(rowb + r) * N + col] = (bf16)v;
                else          Cf[(size_t)(rowb + r) * N + col] = v;
            }
        }
    }
}

// ---------------- 128x64-tile MFMA GEMM, swizzled LDS ------------------------
// requires M%128==0, N%64==0, K%32==0. 1568 blocks at [12544,1024] = 6.1/CU.
template<bool OUT_BF16>
__global__ __launch_bounds__(256)
void gemm_bt_m128n64(const bf16* __restrict__ A, const bf16* __restrict__ BT,
                     void* __restrict__ Cout, const float* __restrict__ bias,
                     int M, int N, int K) {
    __shared__ bf16 Asm[128 * 32];
    __shared__ bf16 Bsm[64 * 32];
    const int tid = threadIdx.x;
    const int wave = tid >> 6, lane = tid & 63;
    const int MT = gridDim.y, NT = gridDim.x;
    const int flat = blockIdx.y * NT + blockIdx.x;
    const int per = 8 * NT;
    const int group = flat / per;
    const int within = flat % per;
    int gm = MT - group * 8; if (gm > 8) gm = 8;
    const int m0 = (group * 8 + within % gm) * 128;
    const int n0 = (within / gm) * 64;
    const int r16 = lane >> 2;
    const int kc  = sw_store(lane);
    const bf16* Ag0 = A  + (size_t)(m0 + wave * 16 + r16) * K + kc;
    const bf16* Ag1 = Ag0 + (size_t)64 * K;
    const bf16* Bg  = BT + (size_t)(n0 + wave * 16 + r16) * K + kc;
    bf16* Al0 = Asm + wave * 512;
    bf16* Al1 = Asm + 2048 + wave * 512;
    bf16* Bl  = Bsm + wave * 512;
    const int qd = lane >> 4, l15 = lane & 15;
    const int wm = (wave >> 1) * 64, wn = (wave & 1) * 32;
    f32x4 acc[4][2] = {};
    for (int k0 = 0; k0 < K; k0 += 32) {
        gld_lds16(Ag0 + k0, Al0);
        gld_lds16(Ag1 + k0, Al1);
        gld_lds16(Bg  + k0, Bl);
        __syncthreads();
        bfv8 af[4], bfr[2];
        #pragma unroll
        for (int i = 0; i < 4; i++) {
            int R = wm + i * 16 + l15;
            af[i] = *(const bfv8*)(Asm + R * 32 + sw_read(R, qd));
        }
        #pragma unroll
        for (int j = 0; j < 2; j++) {
            int R = wn + j * 16 + l15;
            bfr[j] = *(const bfv8*)(Bsm + R * 32 + sw_read(R, qd));
        }
        #pragma unroll
        for (int i = 0; i < 4; i++)
            #pragma unroll
            for (int j = 0; j < 2; j++)
                acc[i][j] = mfma16(af[i], bfr[j], acc[i][j]);
        __syncthreads();
    }
    float* Cf = (float*)Cout;
    bf16*  Cb = (bf16*)Cout;
    #pragma unroll
    for (int i = 0; i < 4; i++) {
        int rowb = m0 + wm + i * 16 + qd * 4;
        #pragma unroll
        for (int j = 0; j < 2; j++) {
            int col = n0 + wn + j * 16 + l15;
            float bv = bias ? bias[col] : 0.0f;
            #pragma unroll
            for (int r = 0; r < 4; r++) {
                float v = acc[i][j][r] + bv;
                if (OUT_BF16) Cb[(size_t)(rowb + r) * N + col] = (bf16)v;
                else          Cf[(size_t)(rowb + r) * N + col] = v;
            }
        }
    }
}

// ---------------- small MFMA GEMM: 64x64 tile, BK=32, 2-level batch ----------
// gld_lds16 staging: rows beyond M/N read unguarded into adjacent workspace
// (caller-audited). Stores are tail-masked. K%32==0.
template<bool OUT_BF16>
__global__ __launch_bounds__(256)
void gemm_bt_small(const bf16* __restrict__ A, long sA1, long sA2, long lda,
                   const bf16* __restrict__ BT, long sB1, long sB2, long ldb,
                   void* __restrict__ Cout, long sC1, long sC2, long ldc,
                   const float* __restrict__ bias,
                   const bf16* __restrict__ resid, long sR1,
                   int M, int N, int K, float alpha, int zdiv) {
    __shared__ bf16 Asm[64 * 32];
    __shared__ bf16 Bsm[64 * 32];
    const int bz = blockIdx.z;
    const int z1 = bz / zdiv, z2 = bz % zdiv;
    A  += (size_t)z1 * sA1 + (size_t)z2 * sA2;
    BT += (size_t)z1 * sB1 + (size_t)z2 * sB2;
    const int tid = threadIdx.x;
    const int wave = tid >> 6, lane = tid & 63;
    const int m0 = blockIdx.y * 64, n0 = blockIdx.x * 64;
    const int r16 = lane >> 2;
    const int kc  = sw_store(lane);
    const int qd = lane >> 4, l15 = lane & 15;
    const bf16* Ag = A  + (size_t)(m0 + wave * 16 + r16) * lda + kc;
    const bf16* Bg = BT + (size_t)(n0 + wave * 16 + r16) * ldb + kc;
    bf16* Al = Asm + wave * 512;
    bf16* Bl = Bsm + wave * 512;
    f32x4 acc[4] = {};
    for (int k0 = 0; k0 < K; k0 += 32) {
        gld_lds16(Ag + k0, Al);
        gld_lds16(Bg + k0, Bl);
        __syncthreads();
        int RA = wave * 16 + l15;
        bfv8 af = *(const bfv8*)(Asm + RA * 32 + sw_read(RA, qd));
        #pragma unroll
        for (int j = 0; j < 4; j++) {
            int R = j * 16 + l15;
            bfv8 bv = *(const bfv8*)(Bsm + R * 32 + sw_read(R, qd));
            acc[j] = mfma16(af, bv, acc[j]);
        }
        __syncthreads();
    }
    float* Cf = (float*)Cout + (size_t)z1 * sC1 + (size_t)z2 * sC2;
    bf16*  Cb = (bf16*)Cout + (size_t)z1 * sC1 + (size_t)z2 * sC2;
    const bf16* rs = resid ? resid + (size_t)z1 * sR1 : nullptr;
    #pragma unroll
    for (int j = 0; j < 4; j++) {
        int col = n0 + j * 16 + l15;
        if (col >= N) continue;
        float bv = bias ? bias[col] : 0.f;
        #pragma unroll
        for (int r = 0; r < 4; r++) {
            int row = m0 + wave * 16 + qd * 4 + r;
            if (row >= M) continue;
            float v = alpha * acc[j][r] + bv;
            if (rs) v += (float)rs[(size_t)row * ldc + col];
            if (OUT_BF16) Cb[(size_t)row * ldc + col] = (bf16)v;
            else          Cf[(size_t)row * ldc + col] = v;
        }
    }
}

// ---------------- small MFMA GEMM: 64x64 tile, BK=64 (K%64==0) ---------------
// Half the barrier pairs of the BK=32 version; identical MFMA order (bit-
// identical results). LDS pitch 64 bf16 (8 chunks/row), XOR swizzle by row&7:
// LDS chunk (r,c) holds global chunk c ^ (r&7); read row R chunk q at LDS
// chunk q ^ (R&7) -> 8 distinct 4-dword windows per 16 rows = 2-way = free.
// Staging per operand per K-step: 2 gld calls, lane covers row lane>>3,
// chunk lane&7. Unguarded staging tails as in BK=32 (caller-audited).
template<bool OUT_BF16>
__global__ __launch_bounds__(256)
void gemm_bt_small64(const bf16* __restrict__ A, long sA1, long sA2, long lda,
                     const bf16* __restrict__ BT, long sB1, long sB2, long ldb,
                     void* __restrict__ Cout, long sC1, long sC2, long ldc,
                     const float* __restrict__ bias,
                     const bf16* __restrict__ resid, long sR1,
                     int M, int N, int K, float alpha, int zdiv) {
    __shared__ bf16 Asm[64 * 64];
    __shared__ bf16 Bsm[64 * 64];
    const int bz = blockIdx.z;
    const int z1 = bz / zdiv, z2 = bz % zdiv;
    A  += (size_t)z1 * sA1 + (size_t)z2 * sA2;
    BT += (size_t)z1 * sB1 + (size_t)z2 * sB2;
    const int tid = threadIdx.x;
    const int wave = tid >> 6, lane = tid & 63;
    const int m0 = blockIdx.y * 64, n0 = blockIdx.x * 64;
    const int r8 = lane >> 3;            // 0..7: row within 8-row staging group
    const int cl = lane & 7;             // LDS chunk within row
    const int kg = (cl ^ r8) * 8;        // global k-offset (bf16) for this lane
    const int qd = lane >> 4, l15 = lane & 15;
    const bf16* Ag0 = A  + (size_t)(m0 + wave * 16 + r8) * lda + kg;
    const bf16* Ag1 = Ag0 + (size_t)8 * lda;
    const bf16* Bg0 = BT + (size_t)(n0 + wave * 16 + r8) * ldb + kg;
    const bf16* Bg1 = Bg0 + (size_t)8 * ldb;
    bf16* Al0 = Asm + wave * 1024;       // 16 rows x 64
    bf16* Al1 = Al0 + 512;               // +8 rows
    bf16* Bl0 = Bsm + wave * 1024;
    bf16* Bl1 = Bl0 + 512;
    f32x4 acc[4] = {};
    for (int k0 = 0; k0 < K; k0 += 64) {
        gld_lds16(Ag0 + k0, Al0);
        gld_lds16(Ag1 + k0, Al1);
        gld_lds16(Bg0 + k0, Bl0);
        gld_lds16(Bg1 + k0, Bl1);
        __syncthreads();
        int RA = wave * 16 + l15, swa = RA & 7;
        bfv8 af0 = *(const bfv8*)(Asm + RA * 64 + ((qd    ) ^ swa) * 8);
        bfv8 af1 = *(const bfv8*)(Asm + RA * 64 + ((qd + 4) ^ swa) * 8);
        #pragma unroll
        for (int j = 0; j < 4; j++) {
            int R = j * 16 + l15, sw = R & 7;
            bfv8 b0 = *(const bfv8*)(Bsm + R * 64 + ((qd    ) ^ sw) * 8);
            bfv8 b1 = *(const bfv8*)(Bsm + R * 64 + ((qd + 4) ^ sw) * 8);
            acc[j] = mfma16(af0, b0, acc[j]);
            acc[j] = mfma16(af1, b1, acc[j]);
        }
        __syncthreads();
    }
    float* Cf = (float*)Cout + (size_t)z1 * sC1 + (size_t)z2 * sC2;
    bf16*  Cb = (bf16*)Cout + (size_t)z1 * sC1 + (size_t)z2 * sC2;
    const bf16* rs = resid ? resid + (size_t)z1 * sR1 : nullptr;
    #pragma unroll
    for (int j = 0; j < 4; j++) {
        int col = n0 + j * 16 + l15;
        if (col >= N) continue;
        float bv = bias ? bias[col] : 0.f;
        #pragma unroll
        for (int r = 0; r < 4; r++) {
            int row = m0 + wave * 16 + qd * 4 + r;
            if (row >= M) continue;
            float v = alpha * acc[j][r] + bv;
            if (rs) v += (float)rs[(size_t)row * ldc + col];
            if (OUT_BF16) Cb[(size_t)row * ldc + col] = (bf16)v;
            else          Cf[(size_t)row * ldc + col] = v;
        }
    }
}

// ------- softmax over rows of 196: fp32 in -> bf16 PADDED out [b][224][224] --
__global__ void softmax196(const float* __restrict__ S, bf16* __restrict__ Apad) {
    __shared__ float red[4];
    int row = blockIdx.x;             // b*196 + n
    int b = row / NP_, n = row % NP_;
    const float* p = S + (size_t)row * NP_;
    int t = threadIdx.x;
    float v = (t < NP_) ? p[t] : -1e30f;
    float m = v;
    #pragma unroll
    for (int o = 32; o > 0; o >>= 1) m = fmaxf(m, __shfl_down(m, o));
    int lane = t & 63, wid = t >> 6;
    if (lane == 0) red[wid] = m;
    __syncthreads();
    m = fmaxf(fmaxf(red[0], red[1]), fmaxf(red[2], red[3]));
    float e = (t < NP_) ? __expf(v - m) : 0.f;
    float s = e;
    #pragma unroll
    for (int o = 32; o > 0; o >>= 1) s += __shfl_down(s, o);
    __syncthreads();
    if (lane == 0) red[wid] = s;
    __syncthreads();
    s = red[0] + red[1] + red[2] + red[3];
    if (t < NPP_) {
        bf16* op = Apad + ((size_t)b * NPP_ + n) * NPP_;
        op[t] = (bf16)((t < NP_) ? (e / s) : 0.f);
    }
}

// ---------------- transpose+convert fp32 [R,C] -> bf16 [C,R] -----------------
__global__ void transpose_conv(const float* __restrict__ in, bf16* __restrict__ out,
                               int R, int Cc) {
    __shared__ float t[32][33];
    int c0 = blockIdx.x * 32, r0 = blockIdx.y * 32;
    int tx = threadIdx.x & 31, ty = threadIdx.x >> 5;   // 32 x 8
    #pragma unroll
    for (int i = 0; i < 4; i++) {
        int r = r0 + ty + i * 8;
        if (r < R && c0 + tx < Cc) t[ty + i * 8][tx] = in[(size_t)r * Cc + c0 + tx];
    }
    __syncthreads();
    #pragma unroll
    for (int i = 0; i < 4; i++) {
        int c = c0 + ty + i * 8, r = r0 + tx;
        if (c < Cc && r < R) out[(size_t)c * R + r] = (bf16)t[tx][ty + i * 8];
    }
}

// ---------------- mean-pool over 196 patches: bf16 in -> bf16 out ------------
__global__ void pool_mean(const bf16* __restrict__ x, bf16* __restrict__ pooled) {
    int b = blockIdx.x;
    int d = blockIdx.y * 256 + threadIdx.x;
    const bf16* p = x + (size_t)b * NP_ * DIM_ + d;
    float s = 0.f;
    for (int n = 0; n < NP_; n++) s += (float)p[(size_t)n * DIM_];
    pooled[(size_t)b * DIM_ + d] = (bf16)(s * (1.0f / NP_));
}

// =============================================================================
extern "C" void kernel_launch(void* const* d_in, const int* in_sizes, int n_in,
                              void* d_out, int out_size, void* d_ws, size_t ws_size,
                              hipStream_t stream) {
    const float* image  = (const float*)d_in[0];
    const float* pos    = (const float*)d_in[1];
    const float* ln_p_g = (const float*)d_in[2];
    const float* ln_p_b = (const float*)d_in[3];
    const float* W_emb  = (const float*)d_in[4];
    const float* b_emb  = (const float*)d_in[5];
    const float* ln_e_g = (const float*)d_in[6];
    const float* ln_e_b = (const float*)d_in[7];
    const float* WV     = (const float*)d_in[8];
    const float* WK     = (const float*)d_in[9];
    const float* WQ     = (const float*)d_in[10];
    const float* ln_g   = (const float*)d_in[11];
    const float* ln_b   = (const float*)d_in[12];
    const float* W_last = (const float*)d_in[13];
    const float* b_last = (const float*)d_in[14];
    float* out = (float*)d_out;

    char* p = (char*)d_ws;
    auto alloc = [&](size_t bytes) { char* r = p; p += (bytes + 255) & ~(size_t)255; return r; };
    // x: bf16 residual stream [12544,1024]
    bf16*  x = (bf16*)alloc((size_t)ROWS_ * DIM_ * 2);
    // attention region: S (fp32) | A_pad | fwT — adjacency required for the
    // A·V staging overrun (A_pad tail -> fwT).
    char*  region = alloc(9834496 + 6422528 + 29360128);
    float* S     = (float*)region;                              // 9,834,496 B
    bf16*  A_pad = (bf16*)(region + 9834496);                   // 6,422,528 B
    bf16*  fwT   = (bf16*)(region + 9834496 + 6422528);         // 29,360,128 B
    // ORDER AUDIT (gld staging overruns): S-gemm B-tail reads ≤123 KB past
    // h_bf (into t_bf); S-gemm A-tail ≤123 KB past t_bf (into WembT); fw-gemm
    // B-tail past h_bf (into t_bf); A·V A-tail ≤27 KB past A_pad (into fwT);
    // classifier N-tail ≤49 KB past WlastT (into pooled). Keep this order.
    bf16*  h_bf  = (bf16*)alloc((size_t)ROWS_ * DIM_ * 2);
    bf16*  t_bf  = (bf16*)alloc((size_t)ROWS_ * DIM_ * 2);
    bf16*  WembT  = (bf16*)alloc((size_t)DIM_ * PD_ * 2);
    bf16*  WQ_bf  = (bf16*)alloc((size_t)DIM_ * DIM_ * 2);     // untransposed bf16
    bf16*  WK_bf  = (bf16*)alloc((size_t)DIM_ * DIM_ * 2);
    bf16*  WqkT   = (bf16*)alloc((size_t)DIM_ * DIM_ * 2);     // (WQ WK^T)^T = WK WQ^T
    bf16*  WVT    = (bf16*)alloc((size_t)VDIM_ * VDIM_ * 2);
    bf16*  WlastT = (bf16*)alloc((size_t)NC_ * DIM_ * 2);
    bf16*  pooled = (bf16*)alloc((size_t)B_ * DIM_ * 2);

    // --- weight prep, once per call ------------------------------------------
    transpose_conv<<<dim3(32, 24), 256, 0, stream>>>(W_emb,  WembT,  PD_,  DIM_);
    conv_bf16<<<1024, 256, 0, stream>>>(WQ, WQ_bf, (size_t)DIM_ * DIM_ / 4);
    conv_bf16<<<1024, 256, 0, stream>>>(WK, WK_bf, (size_t)DIM_ * DIM_ / 4);
    // WqkT[c,d] = sum_e WK[c,e] * WQ[d,e]   (A=WK_bf, BT=WQ_bf)
    gemm_bt_big<true><<<dim3(8, 8), 256, 0, stream>>>(
        WK_bf, WQ_bf, WqkT, nullptr, DIM_, DIM_, DIM_);
    transpose_conv<<<dim3(4, 4),   256, 0, stream>>>(WV,     WVT,    VDIM_, VDIM_);
    transpose_conv<<<dim3(32, 32), 256, 0, stream>>>(W_last, WlastT, DIM_, NC_);

    // --- stem ----------------------------------------------------------------
    patchify_ln<<<ROWS_, 256, 0, stream>>>(image, ln_p_g, ln_p_b, t_bf);
    gemm_bt_big<true><<<dim3(DIM_ / 128, ROWS_ / 128), 256, 0, stream>>>(
        t_bf, WembT, h_bf, b_emb, ROWS_, DIM_, PD_);
    ln_rows<<<ROWS_, 256, 0, stream>>>(h_bf, x, ln_e_g, ln_e_b, pos);

    // --- zero A_pad + fwT (adjacent, 35,782,656 B = 2,236,416 float4) --------
    zero_f4<<<2048, 256, 0, stream>>>((float4*)A_pad, (size_t)35782656 / 16);

    const long XS   = (long)NP_ * DIM_;     // h/t/x per-batch stride
    const long AS   = (long)NP_ * NP_;      // S per-batch stride
    const long APS  = (long)NPP_ * NPP_;    // padded A per-batch stride
    const long FTS  = (long)DIM_ * NPP_;    // fwT per-batch stride
    for (int layer = 0; layer < DEPTH_; layer++) {
        // h = LN(x)
        ln_rows<<<ROWS_, 256, 0, stream>>>(x, h_bf, ln_g, ln_b, nullptr);
        // t = h @ Wqk   (128x64 tiles: 1568 blocks = 6.1/CU)
        gemm_bt_m128n64<true><<<dim3(DIM_ / 64, ROWS_ / 128), 256, 0, stream>>>(
            h_bf, WqkT, t_bf, nullptr, ROWS_, DIM_, DIM_);
        // S = scale * t @ h^T   (batched over b; 64-tile, BK=64: 16 barrier
        // pairs instead of 32)
        gemm_bt_small64<false><<<dim3(4, 4, B_), 256, 0, stream>>>(
            t_bf, XS, 0, DIM_, h_bf, XS, 0, DIM_, S, AS, 0, NP_,
            nullptr, nullptr, 0, NP_, NP_, DIM_, SCALE_, 1);
        // A_pad = softmax(S), cols zero-padded to 224
        softmax196<<<ROWS_, 256, 0, stream>>>(S, A_pad);
        // fwT[b][hd*128+dv][n] = sum_k WVT[dv][k] * h[b][n][hd*128+k];  z=b*8+hd
        gemm_bt_small64<true><<<dim3(4, 2, B_ * HEADS_), 256, 0, stream>>>(
            WVT, 0, 0, VDIM_,
            h_bf, XS, VDIM_, DIM_,
            fwT, FTS, (long)VDIM_ * NPP_, NPP_,
            nullptr, nullptr, 0, VDIM_, NP_, VDIM_, 1.0f, HEADS_);
        // x = A_pad @ fwT^T + h   (batched over b; 64-tile BK=32, K=224)
        gemm_bt_small<true><<<dim3(16, 4, B_), 256, 0, stream>>>(
            A_pad, APS, 0, NPP_, fwT, FTS, 0, NPP_, x, XS, 0, DIM_,
            nullptr, h_bf, XS, NP_, DIM_, NPP_, 1.0f, 1);
    }

    pool_mean<<<dim3(B_, 4), 256, 0, stream>>>(x, pooled);
    gemm_bt_small64<false><<<dim3(16, 1, 1), 256, 0, stream>>>(
        pooled, 0, 0, DIM_, WlastT, 0, 0, DIM_, out, 0, 0, NC_,
        b_last, nullptr, 0, B_, NC_, DIM_, 1.0f, 1);
}